// Round 7
// baseline (12283.856 us; speedup 1.0000x reference)
//
#include <hip/hip_runtime.h>
#include <hip/hip_bf16.h>

typedef unsigned short u16;
typedef __attribute__((ext_vector_type(8))) unsigned short us8;

#define NL 6
#define NH 6
#define NE 384
#define NHS 64
#define NT 256
#define NB 64
#define NV 65
#define NM (NB * NT)          // 16384 tokens
#define SCALE 0.051031036307982884f   // 384^-0.5

static __device__ __forceinline__ float bf2f(u16 u) {
    return __uint_as_float(((unsigned int)u) << 16);
}
static __device__ __forceinline__ u16 f2bf(float f) {
    unsigned int x = __float_as_uint(f);
    unsigned int r = x + 0x7fffu + ((x >> 16) & 1u);   // RNE
    return (u16)(r >> 16);
}

// ---------------- embedding: x = tok_emb[idx] + pos_emb (all f32) ---------------
__global__ __launch_bounds__(256)
void embed_kernel(const int* __restrict__ idx, const float* __restrict__ tok,
                  const float* __restrict__ pos, float* __restrict__ x) {
    int gid = blockIdx.x * 256 + threadIdx.x;          // over NM*NE
    int bt = gid / NE, e = gid % NE;
    int t = bt & (NT - 1);
    x[gid] = tok[idx[bt] * NE + e] + pos[t * NE + e];
}

// ---------------- LayerNorm: f32 x -> bf16 out, one wave per token --------------
__global__ __launch_bounds__(256)
void ln_kernel(const float* __restrict__ x, const float* __restrict__ g,
               const float* __restrict__ b, u16* __restrict__ out) {
    const int wv = threadIdx.x >> 6, lane = threadIdx.x & 63;
    const int token = (blockIdx.x << 2) + wv;
    const float* row = x + (size_t)token * NE;
    float vals[6];
    float s = 0.f;
#pragma unroll
    for (int i = 0; i < 6; ++i) { vals[i] = row[i * 64 + lane]; s += vals[i]; }
#pragma unroll
    for (int off = 32; off >= 1; off >>= 1) s += __shfl_xor(s, off);
    float mean = s * (1.f / NE);
    float s2 = 0.f;
#pragma unroll
    for (int i = 0; i < 6; ++i) { float d = vals[i] - mean; s2 += d * d; }
#pragma unroll
    for (int off = 32; off >= 1; off >>= 1) s2 += __shfl_xor(s2, off);
    float inv = rsqrtf(s2 * (1.f / NE) + 1e-5f);
    u16* orow = out + (size_t)token * NE;
#pragma unroll
    for (int i = 0; i < 6; ++i) {
        int e = i * 64 + lane;
        orow[e] = f2bf((vals[i] - mean) * inv * g[e] + b[e]);
    }
}

// ---------------- GEMM cores (naive; unchanged from R6) --------------------------
// C[M,N] = A[M,K](bf16) @ B[K,N](f32). Block = 128x64 tile; thread = 8 rows x 4 cols.

__global__ __launch_bounds__(256)
void gemm_qkv_kernel(const u16* __restrict__ A,
                     const float* __restrict__ B0, const float* __restrict__ B1,
                     const float* __restrict__ B2,
                     u16* __restrict__ qout, u16* __restrict__ kout,
                     u16* __restrict__ vout) {
    const int tid = threadIdx.x;
    const int nbm = NM >> 7;
    const int bm = blockIdx.x % nbm;
    const int bn = blockIdx.x / nbm;           // [0,18)
    const int m0 = bm << 7, n0 = bn << 6;
    const int which = bn / NH, hh = bn % NH;
    const float* Bb = (which == 0 ? B0 : which == 1 ? B1 : B2) + (size_t)hh * NE * NHS;

    const int tx = tid & 15;        // col group: 4 cols
    const int ty = tid >> 4;        // row group: 8 rows
    float acc[8][4] = {};
    const u16* Ab = A + (size_t)(m0 + ty * 8) * NE;
    const float* Bp = Bb + tx * 4;

    for (int k = 0; k < NE; ++k) {
        const float* br = Bp + (size_t)k * NHS;
        float b0 = br[0], b1 = br[1], b2 = br[2], b3 = br[3];
#pragma unroll
        for (int i = 0; i < 8; ++i) {
            float a = bf2f(Ab[(size_t)i * NE + k]);
            acc[i][0] += a * b0;
            acc[i][1] += a * b1;
            acc[i][2] += a * b2;
            acc[i][3] += a * b3;
        }
    }

    u16* dst = (which == 0) ? qout : (which == 1) ? kout : vout;
#pragma unroll
    for (int i = 0; i < 8; ++i) {
#pragma unroll
        for (int j = 0; j < 4; ++j) {
            int row = m0 + ty * 8 + i;
            int col = n0 + tx * 4 + j;
            int s = col & 63;
            int bb = row >> 8, tt = row & 255;
            dst[((((size_t)bb * NH + hh) << 8) + tt) * NHS + s] = f2bf(acc[i][j]);
        }
    }
}

__global__ __launch_bounds__(256)
void gemm_resid_kernel(const u16* __restrict__ A, const float* __restrict__ B,
                       const int N, const int K,
                       const float* __restrict__ bias, float* __restrict__ resid) {
    const int tid = threadIdx.x;
    const int nbm = NM >> 7;
    const int bm = blockIdx.x % nbm;
    const int bn = blockIdx.x / nbm;
    const int m0 = bm << 7, n0 = bn << 6;

    const int tx = tid & 15;
    const int ty = tid >> 4;
    float acc[8][4] = {};
    const u16* Ab = A + (size_t)(m0 + ty * 8) * K;
    const float* Bp = B + n0 + tx * 4;

    for (int k = 0; k < K; ++k) {
        const float* br = Bp + (size_t)k * N;
        float b0 = br[0], b1 = br[1], b2 = br[2], b3 = br[3];
#pragma unroll
        for (int i = 0; i < 8; ++i) {
            float a = bf2f(Ab[(size_t)i * K + k]);
            acc[i][0] += a * b0;
            acc[i][1] += a * b1;
            acc[i][2] += a * b2;
            acc[i][3] += a * b3;
        }
    }

#pragma unroll
    for (int i = 0; i < 8; ++i) {
#pragma unroll
        for (int j = 0; j < 4; ++j) {
            int row = m0 + ty * 8 + i;
            int col = n0 + tx * 4 + j;
            resid[(size_t)row * N + col] += acc[i][j] + bias[col];
        }
    }
}

__global__ __launch_bounds__(256)
void gemm_relu_kernel(const u16* __restrict__ A, const float* __restrict__ B,
                      const int N, const int K,
                      const float* __restrict__ bias, u16* __restrict__ outb) {
    const int tid = threadIdx.x;
    const int nbm = NM >> 7;
    const int bm = blockIdx.x % nbm;
    const int bn = blockIdx.x / nbm;
    const int m0 = bm << 7, n0 = bn << 6;

    const int tx = tid & 15;
    const int ty = tid >> 4;
    float acc[8][4] = {};
    const u16* Ab = A + (size_t)(m0 + ty * 8) * K;
    const float* Bp = B + n0 + tx * 4;

    for (int k = 0; k < K; ++k) {
        const float* br = Bp + (size_t)k * N;
        float b0 = br[0], b1 = br[1], b2 = br[2], b3 = br[3];
#pragma unroll
        for (int i = 0; i < 8; ++i) {
            float a = bf2f(Ab[(size_t)i * K + k]);
            acc[i][0] += a * b0;
            acc[i][1] += a * b1;
            acc[i][2] += a * b2;
            acc[i][3] += a * b3;
        }
    }

#pragma unroll
    for (int i = 0; i < 8; ++i) {
#pragma unroll
        for (int j = 0; j < 4; ++j) {
            int row = m0 + ty * 8 + i;
            int col = n0 + tx * 4 + j;
            outb[(size_t)row * N + col] = f2bf(fmaxf(acc[i][j] + bias[col], 0.f));
        }
    }
}

// ---------------- attention: K in LDS (32 KB), V from global ---------------------
__global__ __launch_bounds__(256)
void attn_kernel(const u16* __restrict__ q, const u16* __restrict__ k,
                 const u16* __restrict__ v, u16* __restrict__ o) {
    __shared__ __align__(16) u16 sK[NT * NHS];          // 32 KB
    const int tid = threadIdx.x;
    const int bh = blockIdx.x;
    const int b = bh / NH, hh = bh % NH;
    const size_t base = (size_t)bh << 14;   // *T*HS
    const us8* kg = (const us8*)(k + base);
    us8* sk8 = (us8*)sK;
    for (int i = tid; i < (NT * NHS) / 8; i += 256) sk8[i] = kg[i];
    __syncthreads();
    const int t = tid;
    float qr[64];
    {
        const us8* qg = (const us8*)(q + base + (size_t)t * NHS);
#pragma unroll
        for (int c = 0; c < 8; ++c) {
            us8 tv = qg[c];
#pragma unroll
            for (int j = 0; j < 8; ++j) qr[c * 8 + j] = bf2f(tv[j]);
        }
    }
    float mx = -1e30f, lsum = 0.f;
    float oacc[64];
#pragma unroll
    for (int j = 0; j < 64; ++j) oacc[j] = 0.f;
    const us8* vbase = (const us8*)(v + base);
    for (int u = 0; u <= t; ++u) {
        const us8* kr = (const us8*)(sK + u * NHS);
        float s = 0.f;
#pragma unroll
        for (int c = 0; c < 8; ++c) {
            us8 kv = kr[c];
#pragma unroll
            for (int j = 0; j < 8; ++j) s += qr[c * 8 + j] * bf2f(kv[j]);
        }
        s *= SCALE;
        if (s > mx) {
            float cf = __expf(mx - s);
            lsum *= cf;
#pragma unroll
            for (int j = 0; j < 64; ++j) oacc[j] *= cf;
            mx = s;
        }
        float e = __expf(s - mx);
        lsum += e;
        const us8* vr = vbase + u * 8;
#pragma unroll
        for (int c = 0; c < 8; ++c) {
            us8 vv = vr[c];
#pragma unroll
            for (int j = 0; j < 8; ++j) oacc[c * 8 + j] += e * bf2f(vv[j]);
        }
    }
    float inv = 1.f / lsum;
    u16* orow = o + ((size_t)(b * NT + t)) * NE + hh * NHS;
#pragma unroll
    for (int c = 0; c < 8; ++c) {
        us8 pack;
#pragma unroll
        for (int j = 0; j < 8; ++j) pack[j] = f2bf(oacc[c * 8 + j] * inv);
        *(us8*)(orow + c * 8) = pack;
    }
}

// ---------------- LM head: logits = xf(bf16) @ Wlm(f32) + blm, *** f32 out *** ---
__global__ __launch_bounds__(256)
void lmhead_kernel(const u16* __restrict__ xf, const float* __restrict__ Wlm,
                   const float* __restrict__ blm, float* __restrict__ out) {
    int gid = blockIdx.x * 256 + threadIdx.x;     // over NM*NV exactly
    int m = gid / NV, vv = gid % NV;
    const u16* xr = xf + (size_t)m * NE;
    float acc = blm[vv];
#pragma unroll 4
    for (int kk = 0; kk < NE; ++kk)
        acc += bf2f(xr[kk]) * Wlm[kk * NV + vv];
    out[gid] = acc;
}

// ---------------- loss: -mean logp[target] (f32 logits) --------------------------
__global__ __launch_bounds__(256)
void loss_kernel(const float* __restrict__ logits, const int* __restrict__ targets,
                 float* __restrict__ acc) {
    int t = blockIdx.x * 256 + threadIdx.x;       // 16384 threads
    const float* row = logits + (size_t)t * NV;
    float mx = -1e30f;
    for (int i = 0; i < NV; ++i) mx = fmaxf(mx, row[i]);
    float se = 0.f;
    for (int i = 0; i < NV; ++i) se += __expf(row[i] - mx);
    float li = __logf(se) + mx - row[targets[t]];
#pragma unroll
    for (int off = 32; off >= 1; off >>= 1) li += __shfl_xor(li, off);
    if ((threadIdx.x & 63) == 0) atomicAdd(acc, li);
}

__global__ void loss_final_kernel(const float* __restrict__ acc, float* __restrict__ out) {
    out[0] = acc[0] * (1.f / (float)NM);
}

// ---------------- diagnosis probes (f32 signal codes) ----------------------------
__global__ void snap_kernel(const u16* __restrict__ src, float* __restrict__ dst) {
    if (threadIdx.x == 0 && blockIdx.x == 0) {
        float s = 0.f;
        for (int j = 0; j < 64; ++j) s += fabsf(bf2f(src[j]));
        *dst = s;
    }
}
__global__ void probe_kernel(const float* __restrict__ scr,
                             const float* __restrict__ Wq, float* __restrict__ out0) {
    if (threadIdx.x == 0 && blockIdx.x == 0) {
        float sum = 0.f;
        if (scr[0] > 1e-6f) sum += 10.f;   // qb has real data
        if (scr[1] > 1e-6f) sum += 20.f;   // ob has real data
        if (scr[2] > 1e-6f) sum += 40.f;   // ub has real data
        float sw = 0.f;
        for (int j = 0; j < 64; ++j) sw += fabsf(Wq[j]);
        if (sw < 1e-4f) sum += 5.f;        // weight input reads as zero
        if (sum < 70.f) out0[0] = 200.f + sum;
    }
}
__global__ void code_kernel(float* __restrict__ out0, float code) {
    if (threadIdx.x == 0 && blockIdx.x == 0) out0[0] = code;
}

// ================================ host ==========================================
extern "C" void kernel_launch(void* const* d_in, const int* in_sizes, int n_in,
                              void* d_out, int out_size, void* d_ws, size_t ws_size,
                              hipStream_t stream) {
    const int*   idx      = (const int*)d_in[0];
    const int*   targets  = (const int*)d_in[1];
    const float* tok_emb  = (const float*)d_in[2];
    const float* pos_emb  = (const float*)d_in[3];
    const float* Wq       = (const float*)d_in[4];
    const float* Wk       = (const float*)d_in[5];
    const float* Wv       = (const float*)d_in[6];
    const float* Wproj    = (const float*)d_in[7];
    const float* bproj    = (const float*)d_in[8];
    const float* ln1_g    = (const float*)d_in[9];
    const float* ln1_b    = (const float*)d_in[10];
    const float* ln2_g    = (const float*)d_in[11];
    const float* ln2_b    = (const float*)d_in[12];
    const float* W1       = (const float*)d_in[13];
    const float* b1       = (const float*)d_in[14];
    const float* W2       = (const float*)d_in[15];
    const float* b2       = (const float*)d_in[16];
    const float* lnf_g    = (const float*)d_in[17];
    const float* lnf_b    = (const float*)d_in[18];
    const float* Wlm      = (const float*)d_in[19];
    const float* blm      = (const float*)d_in[20];
    float* out = (float*)d_out;          // *** reference output dtype: float32 ***

    // ---- input-identity verification (host-side, free) ----
    static const int expect[21] = {
        16384, 16384, 24960, 98304, 884736, 884736, 884736, 884736, 2304,
        2304, 2304, 2304, 2304, 3538944, 9216, 3538944, 2304, 384, 384,
        24960, 65};
    if (n_in < 21) {
        code_kernel<<<1, 1, 0, stream>>>(out, 990.f);
        return;
    }
    for (int i = 0; i < 21; ++i) {
        if (in_sizes[i] != expect[i]) {
            code_kernel<<<1, 1, 0, stream>>>(out, 1000.f + 10.f * i);
            return;
        }
    }

    // ---- workspace layout (identical to R6, ~88.1 MB) ----
    char* ws = (char*)d_ws;
    size_t off = 0;
    auto alloc = [&](size_t bytes) -> void* {
        void* p = ws + off;
        off += (bytes + 255) & ~(size_t)255;
        return p;
    };
    const size_t S = (size_t)NM * NE * 2;          // 12.58 MB
    float* lossacc = (float*)alloc(256);           // [0]=loss acc, [8..10]=probe scratch
    float* x       = (float*)alloc((size_t)NM * NE * 4);   // f32 residual master
    u16*   h       = (u16*)alloc(S);                        // LN output
    u16*   region  = (u16*)alloc(4 * S);                    // q|k|v|o, overlaid by ub
    u16*   qb = region;
    u16*   kb = region + NM * NE;
    u16*   vb = region + 2 * (size_t)NM * NE;
    u16*   ob = region + 3 * (size_t)NM * NE;
    u16*   ub = region;                                     // [NM, 4*NE] overlays q|k|v|o
    float* scratch = lossacc + 8;

    if (ws_size < off) {
        code_kernel<<<1, 1, 0, stream>>>(out, 999.f);
        return;
    }

    hipMemsetAsync(lossacc, 0, 4, stream);

    embed_kernel<<<(NM * NE) / 256, 256, 0, stream>>>(idx, tok_emb, pos_emb, x);

    const int gLN = NM / 4;
    for (int l = 0; l < NL; ++l) {
        const size_t wqkv = (size_t)l * NH * NE * NHS;
        ln_kernel<<<gLN, 256, 0, stream>>>(x, ln1_g + l * NE, ln1_b + l * NE, h);
        gemm_qkv_kernel<<<(NM / 128) * (3 * NE / 64), 256, 0, stream>>>(
            h, Wq + wqkv, Wk + wqkv, Wv + wqkv, qb, kb, vb);
        if (l == 0) snap_kernel<<<1, 64, 0, stream>>>(qb + 4096, scratch + 0);
        attn_kernel<<<NB * NH, 256, 0, stream>>>(qb, kb, vb, ob);
        if (l == 0) snap_kernel<<<1, 64, 0, stream>>>(ob + 4096, scratch + 1);
        gemm_resid_kernel<<<(NM / 128) * (NE / 64), 256, 0, stream>>>(
            ob, Wproj + (size_t)l * NE * NE, NE, NE, bproj + l * NE, x);
        ln_kernel<<<gLN, 256, 0, stream>>>(x, ln2_g + l * NE, ln2_b + l * NE, h);
        gemm_relu_kernel<<<(NM / 128) * (4 * NE / 64), 256, 0, stream>>>(
            h, W1 + (size_t)l * NE * 4 * NE, 4 * NE, NE, b1 + l * 4 * NE, ub);
        if (l == 0) snap_kernel<<<1, 64, 0, stream>>>(ub + 4096, scratch + 2);
        gemm_resid_kernel<<<(NM / 128) * (NE / 64), 256, 0, stream>>>(
            ub, W2 + (size_t)l * NE * 4 * NE, NE, 4 * NE, b2 + l * NE, x);
    }

    ln_kernel<<<gLN, 256, 0, stream>>>(x, lnf_g, lnf_b, h);
    lmhead_kernel<<<(NM * NV) / 256, 256, 0, stream>>>(h, Wlm, blm, out);
    loss_kernel<<<NM / 256, 256, 0, stream>>>(out, targets, lossacc);
    if (out_size > NM * NV)
        loss_final_kernel<<<1, 1, 0, stream>>>(lossacc, out + (size_t)NM * NV);

    // diagnosis probe: only touches out[0] if a pipeline stage is dead
    probe_kernel<<<1, 64, 0, stream>>>(scratch, Wq, out);
}

// Round 8
// 3162.207 us; speedup vs baseline: 3.8846x; 3.8846x over previous
//
#include <hip/hip_runtime.h>
#include <hip/hip_bf16.h>

typedef unsigned short u16;
typedef __attribute__((ext_vector_type(8))) unsigned short us8;
typedef __attribute__((ext_vector_type(8))) short mfma_in8;   // 8 bf16 in 4 VGPRs
typedef __attribute__((ext_vector_type(4))) float f32x4;

#define NL 6
#define NH 6
#define NE 384
#define NHS 64
#define NT 256
#define NB 64
#define NV 65
#define NM (NB * NT)          // 16384 tokens
#define SCALE 0.051031036307982884f   // 384^-0.5
#define LDP 40                // padded LDS row stride (u16), 16B-aligned, non-pow2

static __device__ __forceinline__ float bf2f(u16 u) {
    return __uint_as_float(((unsigned int)u) << 16);
}
static __device__ __forceinline__ u16 f2bf(float f) {
    unsigned int x = __float_as_uint(f);
    unsigned int r = x + 0x7fffu + ((x >> 16) & 1u);   // RNE
    return (u16)(r >> 16);
}

// ---------------- embedding ------------------------------------------------------
__global__ __launch_bounds__(256)
void embed_kernel(const int* __restrict__ idx, const float* __restrict__ tok,
                  const float* __restrict__ pos, float* __restrict__ x) {
    int gid = blockIdx.x * 256 + threadIdx.x;          // over NM*NE
    int bt = gid / NE, e = gid % NE;
    int t = bt & (NT - 1);
    x[gid] = tok[idx[bt] * NE + e] + pos[t * NE + e];
}

// ---------------- LayerNorm: f32 x -> bf16 out, one wave per token --------------
__global__ __launch_bounds__(256)
void ln_kernel(const float* __restrict__ x, const float* __restrict__ g,
               const float* __restrict__ b, u16* __restrict__ out) {
    const int wv = threadIdx.x >> 6, lane = threadIdx.x & 63;
    const int token = (blockIdx.x << 2) + wv;
    const float* row = x + (size_t)token * NE;
    float vals[6];
    float s = 0.f;
#pragma unroll
    for (int i = 0; i < 6; ++i) { vals[i] = row[i * 64 + lane]; s += vals[i]; }
#pragma unroll
    for (int off = 32; off >= 1; off >>= 1) s += __shfl_xor(s, off);
    float mean = s * (1.f / NE);
    float s2 = 0.f;
#pragma unroll
    for (int i = 0; i < 6; ++i) { float d = vals[i] - mean; s2 += d * d; }
#pragma unroll
    for (int off = 32; off >= 1; off >>= 1) s2 += __shfl_xor(s2, off);
    float inv = rsqrtf(s2 * (1.f / NE) + 1e-5f);
    u16* orow = out + (size_t)token * NE;
#pragma unroll
    for (int i = 0; i < 6; ++i) {
        int e = i * 64 + lane;
        orow[e] = f2bf((vals[i] - mean) * inv * g[e] + b[e]);
    }
}

// ---------------- MFMA GEMM core: C[128,64] tile = A(bf16) @ B(f32,[K,N]) --------
// 256 threads = 4 waves (2x2), wave tile 64x32, BK=32. B transposed+bf16-cast in LDS.
// Verified mappings (m89): A-frag A[m=l16][k=quad*8+j]; C/D col=l16, row=quad*4+r.
struct TileAcc { f32x4 acc[4][2]; };

static __device__ __forceinline__ void gemm_tile_core(
        const u16* __restrict__ A, const float* __restrict__ Bb,
        int m0, int nb0, int K, int ldb, TileAcc& T) {
    __shared__ __align__(16) u16 smA[128 * LDP];
    __shared__ __align__(16) u16 smB[64 * LDP];
    const int tid = threadIdx.x;
    const int wv = tid >> 6, lane = tid & 63;
    const int wm = wv & 1, wn = wv >> 1;
    const int quad = lane >> 4, l16 = lane & 15;
    const u16* Ab = A + (size_t)m0 * K;
    const int ar = tid >> 2, ac = (tid & 3) << 3;   // A: row, col-offset (8 elems)
    const int bk = tid >> 3, bc = (tid & 7) << 3;   // B: k-row, n-offset (8 elems)

    for (int k0 = 0; k0 < K; k0 += 32) {
        us8 a0 = *(const us8*)(Ab + (size_t)ar * K + k0 + ac);
        us8 a1 = *(const us8*)(Ab + (size_t)(ar + 64) * K + k0 + ac);
        const float* bp = Bb + (size_t)(k0 + bk) * ldb + nb0 + bc;
        float4 bv0 = *(const float4*)bp;
        float4 bv1 = *(const float4*)(bp + 4);
        __syncthreads();
        *(us8*)&smA[ar * LDP + ac] = a0;
        *(us8*)&smA[(ar + 64) * LDP + ac] = a1;
        smB[(bc + 0) * LDP + bk] = f2bf(bv0.x);
        smB[(bc + 1) * LDP + bk] = f2bf(bv0.y);
        smB[(bc + 2) * LDP + bk] = f2bf(bv0.z);
        smB[(bc + 3) * LDP + bk] = f2bf(bv0.w);
        smB[(bc + 4) * LDP + bk] = f2bf(bv1.x);
        smB[(bc + 5) * LDP + bk] = f2bf(bv1.y);
        smB[(bc + 6) * LDP + bk] = f2bf(bv1.z);
        smB[(bc + 7) * LDP + bk] = f2bf(bv1.w);
        __syncthreads();
        mfma_in8 af[4], bfr[2];
#pragma unroll
        for (int im = 0; im < 4; ++im)
            af[im] = *(const mfma_in8*)&smA[(wm * 64 + im * 16 + l16) * LDP + quad * 8];
#pragma unroll
        for (int in = 0; in < 2; ++in)
            bfr[in] = *(const mfma_in8*)&smB[(wn * 32 + in * 16 + l16) * LDP + quad * 8];
#pragma unroll
        for (int im = 0; im < 4; ++im)
#pragma unroll
            for (int in = 0; in < 2; ++in)
                T.acc[im][in] = __builtin_amdgcn_mfma_f32_16x16x32_bf16(
                    af[im], bfr[in], T.acc[im][in], 0, 0, 0);
    }
}

// QKV: B per-head Wq/Wk/Wv (H,E,HS); scatter C to q/k/v [B,H,T,HS]
__global__ __launch_bounds__(256)
void gemm_qkv_kernel(const u16* __restrict__ A,
                     const float* __restrict__ B0, const float* __restrict__ B1,
                     const float* __restrict__ B2,
                     u16* __restrict__ qout, u16* __restrict__ kout,
                     u16* __restrict__ vout) {
    const int nbm = NM >> 7;
    const int bm = blockIdx.x % nbm, bn = blockIdx.x / nbm;   // bn in [0,18)
    const int m0 = bm << 7;
    const int which = bn / NH, hh = bn % NH;
    const float* Bb = (which == 0 ? B0 : which == 1 ? B1 : B2) + (size_t)hh * NE * NHS;
    TileAcc T = {};
    gemm_tile_core(A, Bb, m0, 0, NE, NHS, T);
    const int lane = threadIdx.x & 63, wv = threadIdx.x >> 6;
    const int wm = wv & 1, wn = wv >> 1;
    const int quad = lane >> 4, l16 = lane & 15;
    u16* dst = (which == 0) ? qout : (which == 1) ? kout : vout;
#pragma unroll
    for (int im = 0; im < 4; ++im)
#pragma unroll
        for (int in = 0; in < 2; ++in)
#pragma unroll
            for (int r = 0; r < 4; ++r) {
                int row = m0 + wm * 64 + im * 16 + quad * 4 + r;
                int s = wn * 32 + in * 16 + l16;              // 0..63 within head
                int bb = row >> 8, tt = row & 255;
                dst[((((size_t)bb * NH + hh) << 8) + tt) * NHS + s] =
                    f2bf(T.acc[im][in][r]);
            }
}

// resid: resid[row*N+col] += C + bias[col]
__global__ __launch_bounds__(256)
void gemm_resid_kernel(const u16* __restrict__ A, const float* __restrict__ B,
                       const int N, const int K,
                       const float* __restrict__ bias, float* __restrict__ resid) {
    const int nbm = NM >> 7;
    const int bm = blockIdx.x % nbm, bn = blockIdx.x / nbm;
    const int m0 = bm << 7, n0 = bn << 6;
    TileAcc T = {};
    gemm_tile_core(A, B, m0, n0, K, N, T);
    const int lane = threadIdx.x & 63, wv = threadIdx.x >> 6;
    const int wm = wv & 1, wn = wv >> 1;
    const int quad = lane >> 4, l16 = lane & 15;
#pragma unroll
    for (int im = 0; im < 4; ++im)
#pragma unroll
        for (int in = 0; in < 2; ++in)
#pragma unroll
            for (int r = 0; r < 4; ++r) {
                int row = m0 + wm * 64 + im * 16 + quad * 4 + r;
                int col = n0 + wn * 32 + in * 16 + l16;
                resid[(size_t)row * N + col] += T.acc[im][in][r] + bias[col];
            }
}

// relu: out = relu(C + bias) bf16
__global__ __launch_bounds__(256)
void gemm_relu_kernel(const u16* __restrict__ A, const float* __restrict__ B,
                      const int N, const int K,
                      const float* __restrict__ bias, u16* __restrict__ outb) {
    const int nbm = NM >> 7;
    const int bm = blockIdx.x % nbm, bn = blockIdx.x / nbm;
    const int m0 = bm << 7, n0 = bn << 6;
    TileAcc T = {};
    gemm_tile_core(A, B, m0, n0, K, N, T);
    const int lane = threadIdx.x & 63, wv = threadIdx.x >> 6;
    const int wm = wv & 1, wn = wv >> 1;
    const int quad = lane >> 4, l16 = lane & 15;
#pragma unroll
    for (int im = 0; im < 4; ++im)
#pragma unroll
        for (int in = 0; in < 2; ++in)
#pragma unroll
            for (int r = 0; r < 4; ++r) {
                int row = m0 + wm * 64 + im * 16 + quad * 4 + r;
                int col = n0 + wn * 32 + in * 16 + l16;
                outb[(size_t)row * N + col] =
                    f2bf(fmaxf(T.acc[im][in][r] + bias[col], 0.f));
            }
}

// ---------------- attention: block = (b,h,quarter); 4 lanes per query ------------
// lane group (tid = qlocal*4 + hq) owns HS/K segment [hq*16, hq*16+16).
__global__ __launch_bounds__(256)
void attn_kernel(const u16* __restrict__ q, const u16* __restrict__ k,
                 const u16* __restrict__ v, u16* __restrict__ o) {
    __shared__ __align__(16) u16 sK[NT * NHS];          // 32 KB
    const int tid = threadIdx.x;
    const int bh = blockIdx.x >> 2, qq = blockIdx.x & 3;
    const int b = bh / NH, hh = bh % NH;
    const int q0 = qq << 6;
    const size_t base = (size_t)bh << 14;   // *T*HS
    const int krows = q0 + 64;              // K rows needed (causal)
    {
        const us8* kg = (const us8*)(k + base);
        us8* sk8 = (us8*)sK;
        for (int i = tid; i < krows * 8; i += 256) sk8[i] = kg[i];
    }
    __syncthreads();
    const int qi = q0 + (tid >> 2);         // this lane's query row
    const int hq = tid & 3;                 // 16-element segment
    float qr[16];
    {
        const us8* qg = (const us8*)(q + base + (size_t)qi * NHS + hq * 16);
        us8 t0 = qg[0], t1 = qg[1];
#pragma unroll
        for (int j = 0; j < 8; ++j) { qr[j] = bf2f(t0[j]); qr[8 + j] = bf2f(t1[j]); }
    }
    float mx = -1e30f, lsum = 0.f;
    float oacc[16];
#pragma unroll
    for (int j = 0; j < 16; ++j) oacc[j] = 0.f;
    const us8* vbase = (const us8*)(v + base);
    for (int u = 0; u <= qi; ++u) {
        const us8* kr = (const us8*)(sK + u * NHS + hq * 16);
        us8 k0 = kr[0], k1 = kr[1];
        float s0 = 0.f, s1 = 0.f, s2 = 0.f, s3 = 0.f;
#pragma unroll
        for (int j = 0; j < 4; ++j) {
            s0 += qr[j] * bf2f(k0[j]);
            s1 += qr[4 + j] * bf2f(k0[4 + j]);
            s2 += qr[8 + j] * bf2f(k1[j]);
            s3 += qr[12 + j] * bf2f(k1[4 + j]);
        }
        float s = (s0 + s1) + (s2 + s3);
        s += __shfl_xor(s, 1);
        s += __shfl_xor(s, 2);              // full dot in all 4 lanes of the group
        s *= SCALE;
        if (s > mx) {
            float cf = __expf(mx - s);
            lsum *= cf;
#pragma unroll
            for (int j = 0; j < 16; ++j) oacc[j] *= cf;
            mx = s;
        }
        float e = __expf(s - mx);
        lsum += e;
        const us8* vr = vbase + u * 8 + hq * 2;
        us8 v0 = vr[0], v1 = vr[1];
#pragma unroll
        for (int j = 0; j < 8; ++j) {
            oacc[j] += e * bf2f(v0[j]);
            oacc[8 + j] += e * bf2f(v1[j]);
        }
    }
    float inv = 1.f / lsum;
    u16* orow = o + ((size_t)(b * NT + qi)) * NE + hh * NHS + hq * 16;
    us8 p0, p1;
#pragma unroll
    for (int j = 0; j < 8; ++j) {
        p0[j] = f2bf(oacc[j] * inv);
        p1[j] = f2bf(oacc[8 + j] * inv);
    }
    *(us8*)orow = p0;
    *(us8*)(orow + 8) = p1;
}

// ---------------- LM head: logits = xf(bf16) @ Wlm(f32) + blm, f32 out ----------
__global__ __launch_bounds__(256)
void lmhead_kernel(const u16* __restrict__ xf, const float* __restrict__ Wlm,
                   const float* __restrict__ blm, float* __restrict__ out) {
    int gid = blockIdx.x * 256 + threadIdx.x;     // over NM*NV exactly
    int m = gid / NV, vv = gid % NV;
    const u16* xr = xf + (size_t)m * NE;
    float acc = blm[vv];
#pragma unroll 4
    for (int kk = 0; kk < NE; ++kk)
        acc += bf2f(xr[kk]) * Wlm[kk * NV + vv];
    out[gid] = acc;
}

// ---------------- loss ------------------------------------------------------------
__global__ __launch_bounds__(256)
void loss_kernel(const float* __restrict__ logits, const int* __restrict__ targets,
                 float* __restrict__ acc) {
    int t = blockIdx.x * 256 + threadIdx.x;       // 16384 threads
    const float* row = logits + (size_t)t * NV;
    float mx = -1e30f;
    for (int i = 0; i < NV; ++i) mx = fmaxf(mx, row[i]);
    float se = 0.f;
    for (int i = 0; i < NV; ++i) se += __expf(row[i] - mx);
    float li = __logf(se) + mx - row[targets[t]];
#pragma unroll
    for (int off = 32; off >= 1; off >>= 1) li += __shfl_xor(li, off);
    if ((threadIdx.x & 63) == 0) atomicAdd(acc, li);
}

__global__ void loss_final_kernel(const float* __restrict__ acc, float* __restrict__ out) {
    out[0] = acc[0] * (1.f / (float)NM);
}

__global__ void code_kernel(float* __restrict__ out0, float code) {
    if (threadIdx.x == 0 && blockIdx.x == 0) out0[0] = code;
}

// ================================ host ==========================================
extern "C" void kernel_launch(void* const* d_in, const int* in_sizes, int n_in,
                              void* d_out, int out_size, void* d_ws, size_t ws_size,
                              hipStream_t stream) {
    const int*   idx      = (const int*)d_in[0];
    const int*   targets  = (const int*)d_in[1];
    const float* tok_emb  = (const float*)d_in[2];
    const float* pos_emb  = (const float*)d_in[3];
    const float* Wq       = (const float*)d_in[4];
    const float* Wk       = (const float*)d_in[5];
    const float* Wv       = (const float*)d_in[6];
    const float* Wproj    = (const float*)d_in[7];
    const float* bproj    = (const float*)d_in[8];
    const float* ln1_g    = (const float*)d_in[9];
    const float* ln1_b    = (const float*)d_in[10];
    const float* ln2_g    = (const float*)d_in[11];
    const float* ln2_b    = (const float*)d_in[12];
    const float* W1       = (const float*)d_in[13];
    const float* b1       = (const float*)d_in[14];
    const float* W2       = (const float*)d_in[15];
    const float* b2       = (const float*)d_in[16];
    const float* lnf_g    = (const float*)d_in[17];
    const float* lnf_b    = (const float*)d_in[18];
    const float* Wlm      = (const float*)d_in[19];
    const float* blm      = (const float*)d_in[20];
    float* out = (float*)d_out;          // reference output dtype: float32

    static const int expect[21] = {
        16384, 16384, 24960, 98304, 884736, 884736, 884736, 884736, 2304,
        2304, 2304, 2304, 2304, 3538944, 9216, 3538944, 2304, 384, 384,
        24960, 65};
    if (n_in < 21) { code_kernel<<<1, 1, 0, stream>>>(out, 990.f); return; }
    for (int i = 0; i < 21; ++i)
        if (in_sizes[i] != expect[i]) {
            code_kernel<<<1, 1, 0, stream>>>(out, 1000.f + 10.f * i);
            return;
        }

    // ---- workspace layout (~88.1 MB) ----
    char* ws = (char*)d_ws;
    size_t off = 0;
    auto alloc = [&](size_t bytes) -> void* {
        void* p = ws + off;
        off += (bytes + 255) & ~(size_t)255;
        return p;
    };
    const size_t S = (size_t)NM * NE * 2;          // 12.58 MB
    float* lossacc = (float*)alloc(256);
    float* x       = (float*)alloc((size_t)NM * NE * 4);   // f32 residual master
    u16*   h       = (u16*)alloc(S);                        // LN output
    u16*   region  = (u16*)alloc(4 * S);                    // q|k|v|o, overlaid by ub
    u16*   qb = region;
    u16*   kb = region + NM * NE;
    u16*   vb = region + 2 * (size_t)NM * NE;
    u16*   ob = region + 3 * (size_t)NM * NE;
    u16*   ub = region;                                     // [NM,4*NE] overlays q|k|v|o

    if (ws_size < off) { code_kernel<<<1, 1, 0, stream>>>(out, 999.f); return; }

    hipMemsetAsync(lossacc, 0, 4, stream);

    embed_kernel<<<(NM * NE) / 256, 256, 0, stream>>>(idx, tok_emb, pos_emb, x);

    const int gLN = NM / 4;
    for (int l = 0; l < NL; ++l) {
        const size_t wqkv = (size_t)l * NH * NE * NHS;
        ln_kernel<<<gLN, 256, 0, stream>>>(x, ln1_g + l * NE, ln1_b + l * NE, h);
        gemm_qkv_kernel<<<(NM / 128) * (3 * NE / 64), 256, 0, stream>>>(
            h, Wq + wqkv, Wk + wqkv, Wv + wqkv, qb, kb, vb);
        attn_kernel<<<NB * NH * 4, 256, 0, stream>>>(qb, kb, vb, ob);
        gemm_resid_kernel<<<(NM / 128) * (NE / 64), 256, 0, stream>>>(
            ob, Wproj + (size_t)l * NE * NE, NE, NE, bproj + l * NE, x);
        ln_kernel<<<gLN, 256, 0, stream>>>(x, ln2_g + l * NE, ln2_b + l * NE, h);
        gemm_relu_kernel<<<(NM / 128) * (4 * NE / 64), 256, 0, stream>>>(
            h, W1 + (size_t)l * NE * 4 * NE, 4 * NE, NE, b1 + l * 4 * NE, ub);
        gemm_resid_kernel<<<(NM / 128) * (NE / 64), 256, 0, stream>>>(
            ub, W2 + (size_t)l * NE * 4 * NE, NE, 4 * NE, b2 + l * NE, x);
    }

    ln_kernel<<<gLN, 256, 0, stream>>>(x, lnf_g, lnf_b, h);
    lmhead_kernel<<<(NM * NV) / 256, 256, 0, stream>>>(h, Wlm, blm, out);
    loss_kernel<<<NM / 256, 256, 0, stream>>>(out, targets, lossacc);
    if (out_size > NM * NV)
        loss_final_kernel<<<1, 1, 0, stream>>>(lossacc, out + (size_t)NM * NV);
}

// Round 9
// 1725.738 us; speedup vs baseline: 7.1180x; 1.8324x over previous
//
#include <hip/hip_runtime.h>
#include <hip/hip_bf16.h>

typedef unsigned short u16;
typedef __attribute__((ext_vector_type(8))) unsigned short us8;
typedef __attribute__((ext_vector_type(8))) short mfma_in8;   // 8 bf16 in 4 VGPRs
typedef __attribute__((ext_vector_type(4))) float f32x4;

#define NL 6
#define NH 6
#define NE 384
#define NHS 64
#define NT 256
#define NB 64
#define NV 65
#define NM (NB * NT)          // 16384 tokens
#define SCALE 0.051031036307982884f   // 384^-0.5
#define LDP 40                // GEMM LDS row stride (u16)
#define VTP 264               // V^T LDS row stride (u16): 2-way only
#define PSP 44                // P-tile LDS row stride (u16): conflict-free b128

static __device__ __forceinline__ float bf2f(u16 u) {
    return __uint_as_float(((unsigned int)u) << 16);
}
static __device__ __forceinline__ u16 f2bf(float f) {
    unsigned int x = __float_as_uint(f);
    unsigned int r = x + 0x7fffu + ((x >> 16) & 1u);   // RNE
    return (u16)(r >> 16);
}

// ---------------- embedding ------------------------------------------------------
__global__ __launch_bounds__(256)
void embed_kernel(const int* __restrict__ idx, const float* __restrict__ tok,
                  const float* __restrict__ pos, float* __restrict__ x) {
    int gid = blockIdx.x * 256 + threadIdx.x;          // over NM*NE
    int bt = gid / NE, e = gid % NE;
    int t = bt & (NT - 1);
    x[gid] = tok[idx[bt] * NE + e] + pos[t * NE + e];
}

// ---------------- LayerNorm: f32 x -> bf16 out, one wave per token --------------
__global__ __launch_bounds__(256)
void ln_kernel(const float* __restrict__ x, const float* __restrict__ g,
               const float* __restrict__ b, u16* __restrict__ out) {
    const int wv = threadIdx.x >> 6, lane = threadIdx.x & 63;
    const int token = (blockIdx.x << 2) + wv;
    const float* row = x + (size_t)token * NE;
    float vals[6];
    float s = 0.f;
#pragma unroll
    for (int i = 0; i < 6; ++i) { vals[i] = row[i * 64 + lane]; s += vals[i]; }
#pragma unroll
    for (int off = 32; off >= 1; off >>= 1) s += __shfl_xor(s, off);
    float mean = s * (1.f / NE);
    float s2 = 0.f;
#pragma unroll
    for (int i = 0; i < 6; ++i) { float d = vals[i] - mean; s2 += d * d; }
#pragma unroll
    for (int off = 32; off >= 1; off >>= 1) s2 += __shfl_xor(s2, off);
    float inv = rsqrtf(s2 * (1.f / NE) + 1e-5f);
    u16* orow = out + (size_t)token * NE;
#pragma unroll
    for (int i = 0; i < 6; ++i) {
        int e = i * 64 + lane;
        orow[e] = f2bf((vals[i] - mean) * inv * g[e] + b[e]);
    }
}

// ---------------- MFMA GEMM core: C[128,64] tile = A(bf16) @ B(f32,[K,N]) --------
struct TileAcc { f32x4 acc[4][2]; };

static __device__ __forceinline__ void gemm_tile_core(
        const u16* __restrict__ A, const float* __restrict__ Bb,
        int m0, int nb0, int K, int ldb, TileAcc& T) {
    __shared__ __align__(16) u16 smA[128 * LDP];
    __shared__ __align__(16) u16 smB[64 * LDP];
    const int tid = threadIdx.x;
    const int wv = tid >> 6, lane = tid & 63;
    const int wm = wv & 1, wn = wv >> 1;
    const int quad = lane >> 4, l16 = lane & 15;
    const u16* Ab = A + (size_t)m0 * K;
    const int ar = tid >> 2, ac = (tid & 3) << 3;   // A: row, col-offset (8 elems)
    const int bk = tid >> 3, bc = (tid & 7) << 3;   // B: k-row, n-offset (8 elems)

    for (int k0 = 0; k0 < K; k0 += 32) {
        us8 a0 = *(const us8*)(Ab + (size_t)ar * K + k0 + ac);
        us8 a1 = *(const us8*)(Ab + (size_t)(ar + 64) * K + k0 + ac);
        const float* bp = Bb + (size_t)(k0 + bk) * ldb + nb0 + bc;
        float4 bv0 = *(const float4*)bp;
        float4 bv1 = *(const float4*)(bp + 4);
        __syncthreads();
        *(us8*)&smA[ar * LDP + ac] = a0;
        *(us8*)&smA[(ar + 64) * LDP + ac] = a1;
        smB[(bc + 0) * LDP + bk] = f2bf(bv0.x);
        smB[(bc + 1) * LDP + bk] = f2bf(bv0.y);
        smB[(bc + 2) * LDP + bk] = f2bf(bv0.z);
        smB[(bc + 3) * LDP + bk] = f2bf(bv0.w);
        smB[(bc + 4) * LDP + bk] = f2bf(bv1.x);
        smB[(bc + 5) * LDP + bk] = f2bf(bv1.y);
        smB[(bc + 6) * LDP + bk] = f2bf(bv1.z);
        smB[(bc + 7) * LDP + bk] = f2bf(bv1.w);
        __syncthreads();
        mfma_in8 af[4], bfr[2];
#pragma unroll
        for (int im = 0; im < 4; ++im)
            af[im] = *(const mfma_in8*)&smA[(wm * 64 + im * 16 + l16) * LDP + quad * 8];
#pragma unroll
        for (int in = 0; in < 2; ++in)
            bfr[in] = *(const mfma_in8*)&smB[(wn * 32 + in * 16 + l16) * LDP + quad * 8];
#pragma unroll
        for (int im = 0; im < 4; ++im)
#pragma unroll
            for (int in = 0; in < 2; ++in)
                T.acc[im][in] = __builtin_amdgcn_mfma_f32_16x16x32_bf16(
                    af[im], bfr[in], T.acc[im][in], 0, 0, 0);
    }
}

// QKV: B per-head Wq/Wk/Wv (H,E,HS); scatter C to q/k/v [B,H,T,HS]
__global__ __launch_bounds__(256)
void gemm_qkv_kernel(const u16* __restrict__ A,
                     const float* __restrict__ B0, const float* __restrict__ B1,
                     const float* __restrict__ B2,
                     u16* __restrict__ qout, u16* __restrict__ kout,
                     u16* __restrict__ vout) {
    const int nbm = NM >> 7;
    const int bm = blockIdx.x % nbm, bn = blockIdx.x / nbm;   // bn in [0,18)
    const int m0 = bm << 7;
    const int which = bn / NH, hh = bn % NH;
    const float* Bb = (which == 0 ? B0 : which == 1 ? B1 : B2) + (size_t)hh * NE * NHS;
    TileAcc T = {};
    gemm_tile_core(A, Bb, m0, 0, NE, NHS, T);
    const int lane = threadIdx.x & 63, wv = threadIdx.x >> 6;
    const int wm = wv & 1, wn = wv >> 1;
    const int quad = lane >> 4, l16 = lane & 15;
    u16* dst = (which == 0) ? qout : (which == 1) ? kout : vout;
#pragma unroll
    for (int im = 0; im < 4; ++im)
#pragma unroll
        for (int in = 0; in < 2; ++in)
#pragma unroll
            for (int r = 0; r < 4; ++r) {
                int row = m0 + wm * 64 + im * 16 + quad * 4 + r;
                int s = wn * 32 + in * 16 + l16;              // 0..63 within head
                int bb = row >> 8, tt = row & 255;
                dst[((((size_t)bb * NH + hh) << 8) + tt) * NHS + s] =
                    f2bf(T.acc[im][in][r]);
            }
}

// resid: resid[row*N+col] += C + bias[col]
__global__ __launch_bounds__(256)
void gemm_resid_kernel(const u16* __restrict__ A, const float* __restrict__ B,
                       const int N, const int K,
                       const float* __restrict__ bias, float* __restrict__ resid) {
    const int nbm = NM >> 7;
    const int bm = blockIdx.x % nbm, bn = blockIdx.x / nbm;
    const int m0 = bm << 7, n0 = bn << 6;
    TileAcc T = {};
    gemm_tile_core(A, B, m0, n0, K, N, T);
    const int lane = threadIdx.x & 63, wv = threadIdx.x >> 6;
    const int wm = wv & 1, wn = wv >> 1;
    const int quad = lane >> 4, l16 = lane & 15;
#pragma unroll
    for (int im = 0; im < 4; ++im)
#pragma unroll
        for (int in = 0; in < 2; ++in)
#pragma unroll
            for (int r = 0; r < 4; ++r) {
                int row = m0 + wm * 64 + im * 16 + quad * 4 + r;
                int col = n0 + wn * 32 + in * 16 + l16;
                resid[(size_t)row * N + col] += T.acc[im][in][r] + bias[col];
            }
}

// relu: out = relu(C + bias) bf16
__global__ __launch_bounds__(256)
void gemm_relu_kernel(const u16* __restrict__ A, const float* __restrict__ B,
                      const int N, const int K,
                      const float* __restrict__ bias, u16* __restrict__ outb) {
    const int nbm = NM >> 7;
    const int bm = blockIdx.x % nbm, bn = blockIdx.x / nbm;
    const int m0 = bm << 7, n0 = bn << 6;
    TileAcc T = {};
    gemm_tile_core(A, B, m0, n0, K, N, T);
    const int lane = threadIdx.x & 63, wv = threadIdx.x >> 6;
    const int wm = wv & 1, wn = wv >> 1;
    const int quad = lane >> 4, l16 = lane & 15;
#pragma unroll
    for (int im = 0; im < 4; ++im)
#pragma unroll
        for (int in = 0; in < 2; ++in)
#pragma unroll
            for (int r = 0; r < 4; ++r) {
                int row = m0 + wm * 64 + im * 16 + quad * 4 + r;
                int col = n0 + wn * 32 + in * 16 + l16;
                outb[(size_t)row * N + col] =
                    f2bf(fmaxf(T.acc[im][in][r] + bias[col], 0.f));
            }
}

// ---------------- MFMA flash attention ------------------------------------------
// Block = (b,h), 4 waves. Wave w owns m-tiles t = w + 4*mt (16 rows each),
// round-robin for causal balance. No max-subtraction (scores provably tiny).
// S = Q K^T via mfma (A=Q from global, B=K from global); P -> LDS (wave-private)
// -> A-frag; O += P V via mfma (B = V^T staged in LDS). No barriers in main loop.
static __device__ __forceinline__ f32x4 shflx4(f32x4 v, int off) {
    f32x4 r;
#pragma unroll
    for (int i = 0; i < 4; ++i) r[i] = __shfl_xor(v[i], off);
    return r;
}

__global__ __launch_bounds__(256)
void attn_kernel(const u16* __restrict__ q, const u16* __restrict__ k,
                 const u16* __restrict__ v, u16* __restrict__ o) {
    __shared__ __align__(16) u16 sVt[64 * VTP];       // V^T, ~33.8 KB
    __shared__ __align__(16) u16 sP[4][16 * PSP];     // per-wave P tile, ~5.6 KB
    const int tid = threadIdx.x;
    const int bh = blockIdx.x;
    const int b = bh / NH, hh = bh % NH;
    const size_t base = (size_t)bh << 14;   // *T*HS

    // stage V^T: sVt[hs][key]
    {
        const us8* vg = (const us8*)(v + base);
        const int t0 = tid >> 3, c8 = tid & 7;
#pragma unroll
        for (int i = 0; i < 8; ++i) {
            int tt = t0 + i * 32;
            us8 vv = vg[tt * 8 + c8];
#pragma unroll
            for (int j = 0; j < 8; ++j)
                sVt[(c8 * 8 + j) * VTP + tt] = vv[j];
        }
    }
    __syncthreads();

    const int w = tid >> 6, lane = tid & 63;
    const int quad = lane >> 4, l16 = lane & 15;

    // Q A-frags: mt -> tile t = w + 4mt, rows 16t + l16
    mfma_in8 aq[4][2];
#pragma unroll
    for (int mt = 0; mt < 4; ++mt) {
        const int t = w + 4 * mt;
        const u16* qp = q + base + (size_t)(16 * t + l16) * NHS + quad * 8;
        aq[mt][0] = *(const mfma_in8*)qp;
        aq[mt][1] = *(const mfma_in8*)(qp + 32);
    }

    f32x4 oa[4][4] = {};     // O accumulator, C-layout per (mt, nt)
    f32x4 lsum[4] = {};      // row sums per mt (replicated across l16)
    const f32x4 zero = {};

    const int jmax = ((w + 12) >> 1) + 1;   // max j-tiles over this wave's m-tiles
    for (int j = 0; j < jmax; ++j) {
        // V B-frags for this key tile (shared across mt)
        mfma_in8 bv[4];
#pragma unroll
        for (int nt = 0; nt < 4; ++nt)
            bv[nt] = *(const mfma_in8*)&sVt[(nt * 16 + l16) * VTP + j * 32 + quad * 8];
        // K B-frags from global
        mfma_in8 bk[2][2];
#pragma unroll
        for (int nt = 0; nt < 2; ++nt) {
            const u16* kp = k + base + (size_t)(j * 32 + nt * 16 + l16) * NHS + quad * 8;
            bk[nt][0] = *(const mfma_in8*)kp;
            bk[nt][1] = *(const mfma_in8*)(kp + 32);
        }
#pragma unroll
        for (int mt = 0; mt < 4; ++mt) {
            const int t = w + 4 * mt;
            const int jm = t >> 1;
            if (j > jm) continue;           // wave-uniform
            // S tile [16 rows x 32 keys]
            f32x4 s0 = __builtin_amdgcn_mfma_f32_16x16x32_bf16(aq[mt][0], bk[0][0], zero, 0, 0, 0);
            s0 = __builtin_amdgcn_mfma_f32_16x16x32_bf16(aq[mt][1], bk[0][1], s0, 0, 0, 0);
            f32x4 s1 = __builtin_amdgcn_mfma_f32_16x16x32_bf16(aq[mt][0], bk[1][0], zero, 0, 0, 0);
            s1 = __builtin_amdgcn_mfma_f32_16x16x32_bf16(aq[mt][1], bk[1][1], s1, 0, 0, 0);
            // P = exp(S*SCALE), causal mask -> 0 (only boundary tile needs it)
            float p[2][4];
            const bool boundary = (j == jm);
#pragma unroll
            for (int nt = 0; nt < 2; ++nt)
#pragma unroll
                for (int r = 0; r < 4; ++r) {
                    float sv = (nt ? s1[r] : s0[r]) * SCALE;
                    float e = __expf(sv);
                    if (boundary) {
                        int u = j * 32 + nt * 16 + l16;
                        int R = 16 * t + quad * 4 + r;
                        if (u > R) e = 0.f;
                    }
                    p[nt][r] = e;
                }
            // row sums across 32 cols: combine nt, butterfly over l16
            f32x4 rs;
#pragma unroll
            for (int r = 0; r < 4; ++r) rs[r] = p[0][r] + p[1][r];
            rs += shflx4(rs, 1);
            rs += shflx4(rs, 2);
            rs += shflx4(rs, 4);
            rs += shflx4(rs, 8);
            lsum[mt] += rs;
            // P -> LDS (C-layout scatter), wave-private
#pragma unroll
            for (int nt = 0; nt < 2; ++nt)
#pragma unroll
                for (int r = 0; r < 4; ++r)
                    sP[w][(quad * 4 + r) * PSP + nt * 16 + l16] = f2bf(p[nt][r]);
            // P A-frag (K=32 keys)
            mfma_in8 ap = *(const mfma_in8*)&sP[w][l16 * PSP + quad * 8];
            // O += P V
#pragma unroll
            for (int nt = 0; nt < 4; ++nt)
                oa[mt][nt] = __builtin_amdgcn_mfma_f32_16x16x32_bf16(ap, bv[nt], oa[mt][nt], 0, 0, 0);
        }
    }

    // epilogue: O / l, write to o[B,T,E] at head offset
#pragma unroll
    for (int mt = 0; mt < 4; ++mt) {
        const int t = w + 4 * mt;
        f32x4 inv;
#pragma unroll
        for (int r = 0; r < 4; ++r) inv[r] = 1.f / lsum[mt][r];
#pragma unroll
        for (int nt = 0; nt < 4; ++nt)
#pragma unroll
            for (int r = 0; r < 4; ++r) {
                int row = 16 * t + quad * 4 + r;
                int col = hh * NHS + nt * 16 + l16;
                o[((size_t)(b * NT + row)) * NE + col] = f2bf(oa[mt][nt][r] * inv[r]);
            }
    }
}

// ---------------- LM head: logits = xf(bf16) @ Wlm(f32) + blm, f32 out ----------
__global__ __launch_bounds__(256)
void lmhead_kernel(const u16* __restrict__ xf, const float* __restrict__ Wlm,
                   const float* __restrict__ blm, float* __restrict__ out) {
    int gid = blockIdx.x * 256 + threadIdx.x;     // over NM*NV exactly
    int m = gid / NV, vv = gid % NV;
    const u16* xr = xf + (size_t)m * NE;
    float acc = blm[vv];
#pragma unroll 4
    for (int kk = 0; kk < NE; ++kk)
        acc += bf2f(xr[kk]) * Wlm[kk * NV + vv];
    out[gid] = acc;
}

// ---------------- loss ------------------------------------------------------------
__global__ __launch_bounds__(256)
void loss_kernel(const float* __restrict__ logits, const int* __restrict__ targets,
                 float* __restrict__ acc) {
    int t = blockIdx.x * 256 + threadIdx.x;       // 16384 threads
    const float* row = logits + (size_t)t * NV;
    float mx = -1e30f;
    for (int i = 0; i < NV; ++i) mx = fmaxf(mx, row[i]);
    float se = 0.f;
    for (int i = 0; i < NV; ++i) se += __expf(row[i] - mx);
    float li = __logf(se) + mx - row[targets[t]];
#pragma unroll
    for (int off = 32; off >= 1; off >>= 1) li += __shfl_xor(li, off);
    if ((threadIdx.x & 63) == 0) atomicAdd(acc, li);
}

__global__ void loss_final_kernel(const float* __restrict__ acc, float* __restrict__ out) {
    out[0] = acc[0] * (1.f / (float)NM);
}

__global__ void code_kernel(float* __restrict__ out0, float code) {
    if (threadIdx.x == 0 && blockIdx.x == 0) out0[0] = code;
}

// ================================ host ==========================================
extern "C" void kernel_launch(void* const* d_in, const int* in_sizes, int n_in,
                              void* d_out, int out_size, void* d_ws, size_t ws_size,
                              hipStream_t stream) {
    const int*   idx      = (const int*)d_in[0];
    const int*   targets  = (const int*)d_in[1];
    const float* tok_emb  = (const float*)d_in[2];
    const float* pos_emb  = (const float*)d_in[3];
    const float* Wq       = (const float*)d_in[4];
    const float* Wk       = (const float*)d_in[5];
    const float* Wv       = (const float*)d_in[6];
    const float* Wproj    = (const float*)d_in[7];
    const float* bproj    = (const float*)d_in[8];
    const float* ln1_g    = (const float*)d_in[9];
    const float* ln1_b    = (const float*)d_in[10];
    const float* ln2_g    = (const float*)d_in[11];
    const float* ln2_b    = (const float*)d_in[12];
    const float* W1       = (const float*)d_in[13];
    const float* b1       = (const float*)d_in[14];
    const float* W2       = (const float*)d_in[15];
    const float* b2       = (const float*)d_in[16];
    const float* lnf_g    = (const float*)d_in[17];
    const float* lnf_b    = (const float*)d_in[18];
    const float* Wlm      = (const float*)d_in[19];
    const float* blm      = (const float*)d_in[20];
    float* out = (float*)d_out;          // reference output dtype: float32

    static const int expect[21] = {
        16384, 16384, 24960, 98304, 884736, 884736, 884736, 884736, 2304,
        2304, 2304, 2304, 2304, 3538944, 9216, 3538944, 2304, 384, 384,
        24960, 65};
    if (n_in < 21) { code_kernel<<<1, 1, 0, stream>>>(out, 990.f); return; }
    for (int i = 0; i < 21; ++i)
        if (in_sizes[i] != expect[i]) {
            code_kernel<<<1, 1, 0, stream>>>(out, 1000.f + 10.f * i);
            return;
        }

    // ---- workspace layout (~88.1 MB) ----
    char* ws = (char*)d_ws;
    size_t off = 0;
    auto alloc = [&](size_t bytes) -> void* {
        void* p = ws + off;
        off += (bytes + 255) & ~(size_t)255;
        return p;
    };
    const size_t S = (size_t)NM * NE * 2;          // 12.58 MB
    float* lossacc = (float*)alloc(256);
    float* x       = (float*)alloc((size_t)NM * NE * 4);   // f32 residual master
    u16*   h       = (u16*)alloc(S);                        // LN output
    u16*   region  = (u16*)alloc(4 * S);                    // q|k|v|o, overlaid by ub
    u16*   qb = region;
    u16*   kb = region + NM * NE;
    u16*   vb = region + 2 * (size_t)NM * NE;
    u16*   ob = region + 3 * (size_t)NM * NE;
    u16*   ub = region;                                     // [NM,4*NE] overlays q|k|v|o

    if (ws_size < off) { code_kernel<<<1, 1, 0, stream>>>(out, 999.f); return; }

    hipMemsetAsync(lossacc, 0, 4, stream);

    embed_kernel<<<(NM * NE) / 256, 256, 0, stream>>>(idx, tok_emb, pos_emb, x);

    const int gLN = NM / 4;
    for (int l = 0; l < NL; ++l) {
        const size_t wqkv = (size_t)l * NH * NE * NHS;
        ln_kernel<<<gLN, 256, 0, stream>>>(x, ln1_g + l * NE, ln1_b + l * NE, h);
        gemm_qkv_kernel<<<(NM / 128) * (3 * NE / 64), 256, 0, stream>>>(
            h, Wq + wqkv, Wk + wqkv, Wv + wqkv, qb, kb, vb);
        attn_kernel<<<NB * NH, 256, 0, stream>>>(qb, kb, vb, ob);
        gemm_resid_kernel<<<(NM / 128) * (NE / 64), 256, 0, stream>>>(
            ob, Wproj + (size_t)l * NE * NE, NE, NE, bproj + l * NE, x);
        ln_kernel<<<gLN, 256, 0, stream>>>(x, ln2_g + l * NE, ln2_b + l * NE, h);
        gemm_relu_kernel<<<(NM / 128) * (4 * NE / 64), 256, 0, stream>>>(
            h, W1 + (size_t)l * NE * 4 * NE, 4 * NE, NE, b1 + l * 4 * NE, ub);
        gemm_resid_kernel<<<(NM / 128) * (NE / 64), 256, 0, stream>>>(
            ub, W2 + (size_t)l * NE * 4 * NE, NE, 4 * NE, b2 + l * NE, x);
    }

    ln_kernel<<<gLN, 256, 0, stream>>>(x, lnf_g, lnf_b, h);
    lmhead_kernel<<<(NM * NV) / 256, 256, 0, stream>>>(h, Wlm, blm, out);
    loss_kernel<<<NM / 256, 256, 0, stream>>>(out, targets, lossacc);
    if (out_size > NM * NV)
        loss_final_kernel<<<1, 1, 0, stream>>>(lossacc, out + (size_t)NM * NV);
}

// Round 10
// 1324.130 us; speedup vs baseline: 9.2769x; 1.3033x over previous
//
#include <hip/hip_runtime.h>
#include <hip/hip_bf16.h>

typedef unsigned short u16;
typedef __attribute__((ext_vector_type(8))) unsigned short us8;
typedef __attribute__((ext_vector_type(8))) short mfma_in8;   // 8 bf16 in 4 VGPRs
typedef __attribute__((ext_vector_type(4))) float f32x4;

#define NL 6
#define NH 6
#define NE 384
#define NHS 64
#define NT 256
#define NB 64
#define NV 65
#define NM (NB * NT)          // 16384 tokens
#define SCALE 0.051031036307982884f   // 384^-0.5
#define LDP 40                // old-path GEMM LDS row stride (u16)
#define VTP 264               // V^T LDS row stride (u16)
#define PSP 44                // P-tile LDS row stride (u16)

static __device__ __forceinline__ float bf2f(u16 u) {
    return __uint_as_float(((unsigned int)u) << 16);
}
static __device__ __forceinline__ u16 f2bf(float f) {
    unsigned int x = __float_as_uint(f);
    unsigned int r = x + 0x7fffu + ((x >> 16) & 1u);   // RNE
    return (u16)(r >> 16);
}
static __device__ __forceinline__ void llds16(const u16* g, u16* l) {
    __builtin_amdgcn_global_load_lds(
        (const __attribute__((address_space(1))) void*)g,
        (__attribute__((address_space(3))) void*)l, 16, 0, 0);
}

// ---------------- embedding ------------------------------------------------------
__global__ __launch_bounds__(256)
void embed_kernel(const int* __restrict__ idx, const float* __restrict__ tok,
                  const float* __restrict__ pos, float* __restrict__ x) {
    int gid = blockIdx.x * 256 + threadIdx.x;          // over NM*NE
    int bt = gid / NE, e = gid % NE;
    int t = bt & (NT - 1);
    x[gid] = tok[idx[bt] * NE + e] + pos[t * NE + e];
}

// ---------------- LayerNorm ------------------------------------------------------
__global__ __launch_bounds__(256)
void ln_kernel(const float* __restrict__ x, const float* __restrict__ g,
               const float* __restrict__ b, u16* __restrict__ out) {
    const int wv = threadIdx.x >> 6, lane = threadIdx.x & 63;
    const int token = (blockIdx.x << 2) + wv;
    const float* row = x + (size_t)token * NE;
    float vals[6];
    float s = 0.f;
#pragma unroll
    for (int i = 0; i < 6; ++i) { vals[i] = row[i * 64 + lane]; s += vals[i]; }
#pragma unroll
    for (int off = 32; off >= 1; off >>= 1) s += __shfl_xor(s, off);
    float mean = s * (1.f / NE);
    float s2 = 0.f;
#pragma unroll
    for (int i = 0; i < 6; ++i) { float d = vals[i] - mean; s2 += d * d; }
#pragma unroll
    for (int off = 32; off >= 1; off >>= 1) s2 += __shfl_xor(s2, off);
    float inv = rsqrtf(s2 * (1.f / NE) + 1e-5f);
    u16* orow = out + (size_t)token * NE;
#pragma unroll
    for (int i = 0; i < 6; ++i) {
        int e = i * 64 + lane;
        orow[e] = f2bf((vals[i] - mean) * inv * g[e] + b[e]);
    }
}

// ---------------- weight conversion (fast path) ----------------------------------
// QKV: Wq/Wk/Wv (L,H,E,HS) f32 -> WqkvT (L, 1152, 384) bf16, row n = which*384+hh*64+s
__global__ __launch_bounds__(256)
void convQKV_kernel(const float* __restrict__ Wq, const float* __restrict__ Wk,
                    const float* __restrict__ Wv, u16* __restrict__ dst) {
    int i = blockIdx.x * 256 + threadIdx.x;            // over NL*3*NH*NE*NHS
    int s = i & 63; int rest = i >> 6;
    int e = rest % NE; rest /= NE;
    int hh = rest % NH; rest /= NH;
    int which = rest % 3; int l = rest / 3;
    const float* W = which == 0 ? Wq : which == 1 ? Wk : Wv;
    float v = W[((size_t)(l * NH + hh) * NE + e) * NHS + s];
    dst[((size_t)l * 3 * NE + which * NE + hh * NHS + s) * NE + e] = f2bf(v);
}
// generic per-layer transpose: src [K,N] f32 (layer blockIdx.y) -> dst [N,K] bf16
__global__ __launch_bounds__(256)
void convT_kernel(const float* __restrict__ src, u16* __restrict__ dst,
                  int K, int N) {
    const float* s = src + (size_t)blockIdx.y * K * N;
    u16* d = dst + (size_t)blockIdx.y * K * N;
    int i = blockIdx.x * 256 + threadIdx.x;
    if (i >= K * N) return;
    int k = i / N, n = i % N;
    d[(size_t)n * K + k] = f2bf(s[i]);
}
// Wlm [384,65] f32 -> WlmT [80,384] bf16 (rows 65..79 zero)
__global__ __launch_bounds__(256)
void convLM_kernel(const float* __restrict__ Wlm, u16* __restrict__ dst) {
    int i = blockIdx.x * 256 + threadIdx.x;            // over 80*NE
    if (i >= 80 * NE) return;
    int n = i / NE, k = i % NE;
    dst[i] = f2bf(n < NV ? Wlm[(size_t)k * NV + n] : 0.f);
}

// ---------------- fast MFMA GEMM core: 128x128 tile, BK=32, global_load_lds ------
// A [M,K] bf16, BT [N,K] bf16. 4 waves 2x2, wave tile 64x64.
static __device__ __forceinline__ void gemm128_core(
        const u16* __restrict__ A, const u16* __restrict__ BT,
        int m0, int n0, int K, f32x4 acc[4][4]) {
    __shared__ __align__(16) u16 smA[128 * 32];
    __shared__ __align__(16) u16 smB[128 * 32];
    const int tid = threadIdx.x;
    const int wv = tid >> 6, lane = tid & 63;
    const int wm = wv & 1, wn = wv >> 1;
    const int quad = lane >> 4, l16 = lane & 15;
    for (int k0 = 0; k0 < K; k0 += 32) {
        __syncthreads();   // prior-iter LDS reads done before overwrite
#pragma unroll
        for (int j = 0; j < 2; ++j) {
            int c = tid + j * 256;                     // chunk: row c>>2, quarter c&3
            llds16(A + (size_t)(m0 + (c >> 2)) * K + k0 + ((c & 3) << 3), smA + c * 8);
            llds16(BT + (size_t)(n0 + (c >> 2)) * K + k0 + ((c & 3) << 3), smB + c * 8);
        }
        __syncthreads();   // drains vmcnt -> LDS visible
        mfma_in8 af[4], bf[4];
#pragma unroll
        for (int im = 0; im < 4; ++im)
            af[im] = *(const mfma_in8*)&smA[(wm * 64 + im * 16 + l16) * 32 + quad * 8];
#pragma unroll
        for (int in = 0; in < 4; ++in)
            bf[in] = *(const mfma_in8*)&smB[(wn * 64 + in * 16 + l16) * 32 + quad * 8];
#pragma unroll
        for (int im = 0; im < 4; ++im)
#pragma unroll
            for (int in = 0; in < 4; ++in)
                acc[im][in] = __builtin_amdgcn_mfma_f32_16x16x32_bf16(
                    af[im], bf[in], acc[im][in], 0, 0, 0);
    }
}

__global__ __launch_bounds__(256)
void gemm_qkv_f(const u16* __restrict__ A, const u16* __restrict__ BT,
                u16* __restrict__ qout, u16* __restrict__ kout,
                u16* __restrict__ vout) {
    const int nbm = NM >> 7;
    const int bm = blockIdx.x % nbm, bn = blockIdx.x / nbm;
    const int m0 = bm << 7, n0 = bn << 7;              // N=1152
    f32x4 acc[4][4] = {};
    gemm128_core(A, BT, m0, n0, NE, acc);
    const int lane = threadIdx.x & 63, wv = threadIdx.x >> 6;
    const int wm = wv & 1, wn = wv >> 1;
    const int quad = lane >> 4, l16 = lane & 15;
#pragma unroll
    for (int im = 0; im < 4; ++im)
#pragma unroll
        for (int in = 0; in < 4; ++in)
#pragma unroll
            for (int r = 0; r < 4; ++r) {
                int row = m0 + wm * 64 + im * 16 + quad * 4 + r;
                int col = n0 + wn * 64 + in * 16 + l16;
                int which = col / NE, j = col % NE;
                int hh = j >> 6, s = j & 63;
                int bb = row >> 8, tt = row & 255;
                u16* dst = (which == 0) ? qout : (which == 1) ? kout : vout;
                dst[((((size_t)bb * NH + hh) << 8) + tt) * NHS + s] =
                    f2bf(acc[im][in][r]);
            }
}

__global__ __launch_bounds__(256)
void gemm_resid_f(const u16* __restrict__ A, const u16* __restrict__ BT,
                  const int N, const int K,
                  const float* __restrict__ bias, float* __restrict__ resid) {
    const int nbm = NM >> 7;
    const int bm = blockIdx.x % nbm, bn = blockIdx.x / nbm;
    const int m0 = bm << 7, n0 = bn << 7;
    f32x4 acc[4][4] = {};
    gemm128_core(A, BT, m0, n0, K, acc);
    const int lane = threadIdx.x & 63, wv = threadIdx.x >> 6;
    const int wm = wv & 1, wn = wv >> 1;
    const int quad = lane >> 4, l16 = lane & 15;
#pragma unroll
    for (int im = 0; im < 4; ++im)
#pragma unroll
        for (int in = 0; in < 4; ++in)
#pragma unroll
            for (int r = 0; r < 4; ++r) {
                int row = m0 + wm * 64 + im * 16 + quad * 4 + r;
                int col = n0 + wn * 64 + in * 16 + l16;
                resid[(size_t)row * N + col] += acc[im][in][r] + bias[col];
            }
}

__global__ __launch_bounds__(256)
void gemm_relu_f(const u16* __restrict__ A, const u16* __restrict__ BT,
                 const int N, const int K,
                 const float* __restrict__ bias, u16* __restrict__ outb) {
    const int nbm = NM >> 7;
    const int bm = blockIdx.x % nbm, bn = blockIdx.x / nbm;
    const int m0 = bm << 7, n0 = bn << 7;
    f32x4 acc[4][4] = {};
    gemm128_core(A, BT, m0, n0, K, acc);
    const int lane = threadIdx.x & 63, wv = threadIdx.x >> 6;
    const int wm = wv & 1, wn = wv >> 1;
    const int quad = lane >> 4, l16 = lane & 15;
#pragma unroll
    for (int im = 0; im < 4; ++im)
#pragma unroll
        for (int in = 0; in < 4; ++in)
#pragma unroll
            for (int r = 0; r < 4; ++r) {
                int row = m0 + wm * 64 + im * 16 + quad * 4 + r;
                int col = n0 + wn * 64 + in * 16 + l16;
                outb[(size_t)row * N + col] =
                    f2bf(fmaxf(acc[im][in][r] + bias[col], 0.f));
            }
}

// ---------------- fast lmhead: wave per 16-row m-tile, B from global WlmT --------
__global__ __launch_bounds__(256)
void lmhead_f(const u16* __restrict__ xf, const u16* __restrict__ WlmT,
              const float* __restrict__ blm, float* __restrict__ out) {
    const int w = threadIdx.x >> 6, lane = threadIdx.x & 63;
    const int quad = lane >> 4, l16 = lane & 15;
    const int m0 = (blockIdx.x * 4 + w) * 16;
    f32x4 acc[5] = {};
#pragma unroll 2
    for (int k0 = 0; k0 < NE; k0 += 32) {
        mfma_in8 a = *(const mfma_in8*)(xf + (size_t)(m0 + l16) * NE + k0 + quad * 8);
#pragma unroll
        for (int nt = 0; nt < 5; ++nt) {
            mfma_in8 b = *(const mfma_in8*)(WlmT + (size_t)(nt * 16 + l16) * NE + k0 + quad * 8);
            acc[nt] = __builtin_amdgcn_mfma_f32_16x16x32_bf16(a, b, acc[nt], 0, 0, 0);
        }
    }
#pragma unroll
    for (int nt = 0; nt < 5; ++nt) {
        int col = nt * 16 + l16;
        if (col < NV) {
            float bb = blm[col];
#pragma unroll
            for (int r = 0; r < 4; ++r)
                out[(size_t)(m0 + quad * 4 + r) * NV + col] = acc[nt][r] + bb;
        }
    }
}

// ---------------- OLD PATH (fallback if ws too small): f32-B GEMM core -----------
struct TileAcc { f32x4 acc[4][2]; };
static __device__ __forceinline__ void gemm_tile_core(
        const u16* __restrict__ A, const float* __restrict__ Bb,
        int m0, int nb0, int K, int ldb, TileAcc& T) {
    __shared__ __align__(16) u16 smA[128 * LDP];
    __shared__ __align__(16) u16 smB[64 * LDP];
    const int tid = threadIdx.x;
    const int wv = tid >> 6, lane = tid & 63;
    const int wm = wv & 1, wn = wv >> 1;
    const int quad = lane >> 4, l16 = lane & 15;
    const u16* Ab = A + (size_t)m0 * K;
    const int ar = tid >> 2, ac = (tid & 3) << 3;
    const int bk = tid >> 3, bc = (tid & 7) << 3;
    for (int k0 = 0; k0 < K; k0 += 32) {
        us8 a0 = *(const us8*)(Ab + (size_t)ar * K + k0 + ac);
        us8 a1 = *(const us8*)(Ab + (size_t)(ar + 64) * K + k0 + ac);
        const float* bp = Bb + (size_t)(k0 + bk) * ldb + nb0 + bc;
        float4 bv0 = *(const float4*)bp;
        float4 bv1 = *(const float4*)(bp + 4);
        __syncthreads();
        *(us8*)&smA[ar * LDP + ac] = a0;
        *(us8*)&smA[(ar + 64) * LDP + ac] = a1;
        smB[(bc + 0) * LDP + bk] = f2bf(bv0.x);
        smB[(bc + 1) * LDP + bk] = f2bf(bv0.y);
        smB[(bc + 2) * LDP + bk] = f2bf(bv0.z);
        smB[(bc + 3) * LDP + bk] = f2bf(bv0.w);
        smB[(bc + 4) * LDP + bk] = f2bf(bv1.x);
        smB[(bc + 5) * LDP + bk] = f2bf(bv1.y);
        smB[(bc + 6) * LDP + bk] = f2bf(bv1.z);
        smB[(bc + 7) * LDP + bk] = f2bf(bv1.w);
        __syncthreads();
        mfma_in8 af[4], bfr[2];
#pragma unroll
        for (int im = 0; im < 4; ++im)
            af[im] = *(const mfma_in8*)&smA[(wm * 64 + im * 16 + l16) * LDP + quad * 8];
#pragma unroll
        for (int in = 0; in < 2; ++in)
            bfr[in] = *(const mfma_in8*)&smB[(wn * 32 + in * 16 + l16) * LDP + quad * 8];
#pragma unroll
        for (int im = 0; im < 4; ++im)
#pragma unroll
            for (int in = 0; in < 2; ++in)
                T.acc[im][in] = __builtin_amdgcn_mfma_f32_16x16x32_bf16(
                    af[im], bfr[in], T.acc[im][in], 0, 0, 0);
    }
}
__global__ __launch_bounds__(256)
void gemm_qkv_kernel(const u16* __restrict__ A,
                     const float* __restrict__ B0, const float* __restrict__ B1,
                     const float* __restrict__ B2,
                     u16* __restrict__ qout, u16* __restrict__ kout,
                     u16* __restrict__ vout) {
    const int nbm = NM >> 7;
    const int bm = blockIdx.x % nbm, bn = blockIdx.x / nbm;
    const int m0 = bm << 7;
    const int which = bn / NH, hh = bn % NH;
    const float* Bb = (which == 0 ? B0 : which == 1 ? B1 : B2) + (size_t)hh * NE * NHS;
    TileAcc T = {};
    gemm_tile_core(A, Bb, m0, 0, NE, NHS, T);
    const int lane = threadIdx.x & 63, wv = threadIdx.x >> 6;
    const int wm = wv & 1, wn = wv >> 1;
    const int quad = lane >> 4, l16 = lane & 15;
    u16* dst = (which == 0) ? qout : (which == 1) ? kout : vout;
#pragma unroll
    for (int im = 0; im < 4; ++im)
#pragma unroll
        for (int in = 0; in < 2; ++in)
#pragma unroll
            for (int r = 0; r < 4; ++r) {
                int row = m0 + wm * 64 + im * 16 + quad * 4 + r;
                int s = wn * 32 + in * 16 + l16;
                int bb = row >> 8, tt = row & 255;
                dst[((((size_t)bb * NH + hh) << 8) + tt) * NHS + s] =
                    f2bf(T.acc[im][in][r]);
            }
}
__global__ __launch_bounds__(256)
void gemm_resid_kernel(const u16* __restrict__ A, const float* __restrict__ B,
                       const int N, const int K,
                       const float* __restrict__ bias, float* __restrict__ resid) {
    const int nbm = NM >> 7;
    const int bm = blockIdx.x % nbm, bn = blockIdx.x / nbm;
    const int m0 = bm << 7, n0 = bn << 6;
    TileAcc T = {};
    gemm_tile_core(A, B, m0, n0, K, N, T);
    const int lane = threadIdx.x & 63, wv = threadIdx.x >> 6;
    const int wm = wv & 1, wn = wv >> 1;
    const int quad = lane >> 4, l16 = lane & 15;
#pragma unroll
    for (int im = 0; im < 4; ++im)
#pragma unroll
        for (int in = 0; in < 2; ++in)
#pragma unroll
            for (int r = 0; r < 4; ++r) {
                int row = m0 + wm * 64 + im * 16 + quad * 4 + r;
                int col = n0 + wn * 32 + in * 16 + l16;
                resid[(size_t)row * N + col] += T.acc[im][in][r] + bias[col];
            }
}
__global__ __launch_bounds__(256)
void gemm_relu_kernel(const u16* __restrict__ A, const float* __restrict__ B,
                      const int N, const int K,
                      const float* __restrict__ bias, u16* __restrict__ outb) {
    const int nbm = NM >> 7;
    const int bm = blockIdx.x % nbm, bn = blockIdx.x / nbm;
    const int m0 = bm << 7, n0 = bn << 6;
    TileAcc T = {};
    gemm_tile_core(A, B, m0, n0, K, N, T);
    const int lane = threadIdx.x & 63, wv = threadIdx.x >> 6;
    const int wm = wv & 1, wn = wv >> 1;
    const int quad = lane >> 4, l16 = lane & 15;
#pragma unroll
    for (int im = 0; im < 4; ++im)
#pragma unroll
        for (int in = 0; in < 2; ++in)
#pragma unroll
            for (int r = 0; r < 4; ++r) {
                int row = m0 + wm * 64 + im * 16 + quad * 4 + r;
                int col = n0 + wn * 32 + in * 16 + l16;
                outb[(size_t)row * N + col] =
                    f2bf(fmaxf(T.acc[im][in][r] + bias[col], 0.f));
            }
}
__global__ __launch_bounds__(256)
void lmhead_kernel(const u16* __restrict__ xf, const float* __restrict__ Wlm,
                   const float* __restrict__ blm, float* __restrict__ out) {
    int gid = blockIdx.x * 256 + threadIdx.x;
    int m = gid / NV, vv = gid % NV;
    const u16* xr = xf + (size_t)m * NE;
    float acc = blm[vv];
#pragma unroll 4
    for (int kk = 0; kk < NE; ++kk)
        acc += bf2f(xr[kk]) * Wlm[kk * NV + vv];
    out[gid] = acc;
}

// ---------------- MFMA flash attention (unchanged from R9) ------------------------
static __device__ __forceinline__ f32x4 shflx4(f32x4 v, int off) {
    f32x4 r;
#pragma unroll
    for (int i = 0; i < 4; ++i) r[i] = __shfl_xor(v[i], off);
    return r;
}
__global__ __launch_bounds__(256)
void attn_kernel(const u16* __restrict__ q, const u16* __restrict__ k,
                 const u16* __restrict__ v, u16* __restrict__ o) {
    __shared__ __align__(16) u16 sVt[64 * VTP];
    __shared__ __align__(16) u16 sP[4][16 * PSP];
    const int tid = threadIdx.x;
    const int bh = blockIdx.x;
    const int b = bh / NH, hh = bh % NH;
    const size_t base = (size_t)bh << 14;
    {
        const us8* vg = (const us8*)(v + base);
        const int t0 = tid >> 3, c8 = tid & 7;
#pragma unroll
        for (int i = 0; i < 8; ++i) {
            int tt = t0 + i * 32;
            us8 vv = vg[tt * 8 + c8];
#pragma unroll
            for (int j = 0; j < 8; ++j)
                sVt[(c8 * 8 + j) * VTP + tt] = vv[j];
        }
    }
    __syncthreads();
    const int w = tid >> 6, lane = tid & 63;
    const int quad = lane >> 4, l16 = lane & 15;
    mfma_in8 aq[4][2];
#pragma unroll
    for (int mt = 0; mt < 4; ++mt) {
        const int t = w + 4 * mt;
        const u16* qp = q + base + (size_t)(16 * t + l16) * NHS + quad * 8;
        aq[mt][0] = *(const mfma_in8*)qp;
        aq[mt][1] = *(const mfma_in8*)(qp + 32);
    }
    f32x4 oa[4][4] = {};
    f32x4 lsum[4] = {};
    const f32x4 zero = {};
    const int jmax = ((w + 12) >> 1) + 1;
    for (int j = 0; j < jmax; ++j) {
        mfma_in8 bv[4];
#pragma unroll
        for (int nt = 0; nt < 4; ++nt)
            bv[nt] = *(const mfma_in8*)&sVt[(nt * 16 + l16) * VTP + j * 32 + quad * 8];
        mfma_in8 bk[2][2];
#pragma unroll
        for (int nt = 0; nt < 2; ++nt) {
            const u16* kp = k + base + (size_t)(j * 32 + nt * 16 + l16) * NHS + quad * 8;
            bk[nt][0] = *(const mfma_in8*)kp;
            bk[nt][1] = *(const mfma_in8*)(kp + 32);
        }
#pragma unroll
        for (int mt = 0; mt < 4; ++mt) {
            const int t = w + 4 * mt;
            const int jm = t >> 1;
            if (j > jm) continue;
            f32x4 s0 = __builtin_amdgcn_mfma_f32_16x16x32_bf16(aq[mt][0], bk[0][0], zero, 0, 0, 0);
            s0 = __builtin_amdgcn_mfma_f32_16x16x32_bf16(aq[mt][1], bk[0][1], s0, 0, 0, 0);
            f32x4 s1 = __builtin_amdgcn_mfma_f32_16x16x32_bf16(aq[mt][0], bk[1][0], zero, 0, 0, 0);
            s1 = __builtin_amdgcn_mfma_f32_16x16x32_bf16(aq[mt][1], bk[1][1], s1, 0, 0, 0);
            float p[2][4];
            const bool boundary = (j == jm);
#pragma unroll
            for (int nt = 0; nt < 2; ++nt)
#pragma unroll
                for (int r = 0; r < 4; ++r) {
                    float sv = (nt ? s1[r] : s0[r]) * SCALE;
                    float e = __expf(sv);
                    if (boundary) {
                        int u = j * 32 + nt * 16 + l16;
                        int R = 16 * t + quad * 4 + r;
                        if (u > R) e = 0.f;
                    }
                    p[nt][r] = e;
                }
            f32x4 rs;
#pragma unroll
            for (int r = 0; r < 4; ++r) rs[r] = p[0][r] + p[1][r];
            rs += shflx4(rs, 1);
            rs += shflx4(rs, 2);
            rs += shflx4(rs, 4);
            rs += shflx4(rs, 8);
            lsum[mt] += rs;
#pragma unroll
            for (int nt = 0; nt < 2; ++nt)
#pragma unroll
                for (int r = 0; r < 4; ++r)
                    sP[w][(quad * 4 + r) * PSP + nt * 16 + l16] = f2bf(p[nt][r]);
            mfma_in8 ap = *(const mfma_in8*)&sP[w][l16 * PSP + quad * 8];
#pragma unroll
            for (int nt = 0; nt < 4; ++nt)
                oa[mt][nt] = __builtin_amdgcn_mfma_f32_16x16x32_bf16(ap, bv[nt], oa[mt][nt], 0, 0, 0);
        }
    }
#pragma unroll
    for (int mt = 0; mt < 4; ++mt) {
        const int t = w + 4 * mt;
        f32x4 inv;
#pragma unroll
        for (int r = 0; r < 4; ++r) inv[r] = 1.f / lsum[mt][r];
#pragma unroll
        for (int nt = 0; nt < 4; ++nt)
#pragma unroll
            for (int r = 0; r < 4; ++r) {
                int row = 16 * t + quad * 4 + r;
                int col = hh * NHS + nt * 16 + l16;
                o[((size_t)(b * NT + row)) * NE + col] = f2bf(oa[mt][nt][r] * inv[r]);
            }
    }
}

// ---------------- loss ------------------------------------------------------------
__global__ __launch_bounds__(256)
void loss_kernel(const float* __restrict__ logits, const int* __restrict__ targets,
                 float* __restrict__ acc) {
    int t = blockIdx.x * 256 + threadIdx.x;
    const float* row = logits + (size_t)t * NV;
    float mx = -1e30f;
    for (int i = 0; i < NV; ++i) mx = fmaxf(mx, row[i]);
    float se = 0.f;
    for (int i = 0; i < NV; ++i) se += __expf(row[i] - mx);
    float li = __logf(se) + mx - row[targets[t]];
#pragma unroll
    for (int off = 32; off >= 1; off >>= 1) li += __shfl_xor(li, off);
    if ((threadIdx.x & 63) == 0) atomicAdd(acc, li);
}
__global__ void loss_final_kernel(const float* __restrict__ acc, float* __restrict__ out) {
    out[0] = acc[0] * (1.f / (float)NM);
}
__global__ void code_kernel(float* __restrict__ out0, float code) {
    if (threadIdx.x == 0 && blockIdx.x == 0) out0[0] = code;
}

// ================================ host ==========================================
extern "C" void kernel_launch(void* const* d_in, const int* in_sizes, int n_in,
                              void* d_out, int out_size, void* d_ws, size_t ws_size,
                              hipStream_t stream) {
    const int*   idx      = (const int*)d_in[0];
    const int*   targets  = (const int*)d_in[1];
    const float* tok_emb  = (const float*)d_in[2];
    const float* pos_emb  = (const float*)d_in[3];
    const float* Wq       = (const float*)d_in[4];
    const float* Wk       = (const float*)d_in[5];
    const float* Wv       = (const float*)d_in[6];
    const float* Wproj    = (const float*)d_in[7];
    const float* bproj    = (const float*)d_in[8];
    const float* ln1_g    = (const float*)d_in[9];
    const float* ln1_b    = (const float*)d_in[10];
    const float* ln2_g    = (const float*)d_in[11];
    const float* ln2_b    = (const float*)d_in[12];
    const float* W1       = (const float*)d_in[13];
    const float* b1       = (const float*)d_in[14];
    const float* W2       = (const float*)d_in[15];
    const float* b2       = (const float*)d_in[16];
    const float* lnf_g    = (const float*)d_in[17];
    const float* lnf_b    = (const float*)d_in[18];
    const float* Wlm      = (const float*)d_in[19];
    const float* blm      = (const float*)d_in[20];
    float* out = (float*)d_out;

    static const int expect[21] = {
        16384, 16384, 24960, 98304, 884736, 884736, 884736, 884736, 2304,
        2304, 2304, 2304, 2304, 3538944, 9216, 3538944, 2304, 384, 384,
        24960, 65};
    if (n_in < 21) { code_kernel<<<1, 1, 0, stream>>>(out, 990.f); return; }
    for (int i = 0; i < 21; ++i)
        if (in_sizes[i] != expect[i]) {
            code_kernel<<<1, 1, 0, stream>>>(out, 1000.f + 10.f * i);
            return;
        }

    // ---- workspace layout ----
    char* ws = (char*)d_ws;
    size_t off = 0;
    auto alloc = [&](size_t bytes) -> void* {
        void* p = ws + off;
        off += (bytes + 255) & ~(size_t)255;
        return p;
    };
    const size_t S = (size_t)NM * NE * 2;
    float* lossacc = (float*)alloc(256);
    float* x       = (float*)alloc((size_t)NM * NE * 4);
    u16*   h       = (u16*)alloc(S);
    u16*   region  = (u16*)alloc(4 * S);
    u16*   qb = region;
    u16*   kb = region + NM * NE;
    u16*   vb = region + 2 * (size_t)NM * NE;
    u16*   ob = region + 3 * (size_t)NM * NE;
    u16*   ub = region;
    const size_t base_need = off;
    // fast-path weight buffers (bf16 B^T)
    u16* WqkvT  = (u16*)alloc((size_t)NL * 3 * NE * NE * 2);
    u16* WprojT = (u16*)alloc((size_t)NL * NE * NE * 2);
    u16* W1T    = (u16*)alloc((size_t)NL * NE * 4 * NE * 2);
    u16* W2T    = (u16*)alloc((size_t)NL * NE * 4 * NE * 2);
    u16* WlmT   = (u16*)alloc((size_t)80 * NE * 2);
    const size_t fast_need = off;

    const bool fast = (ws_size >= fast_need);
    if (!fast && ws_size < base_need) {
        code_kernel<<<1, 1, 0, stream>>>(out, 999.f);
        return;
    }

    hipMemsetAsync(lossacc, 0, 4, stream);
    embed_kernel<<<(NM * NE) / 256, 256, 0, stream>>>(idx, tok_emb, pos_emb, x);

    if (fast) {
        convQKV_kernel<<<(NL * 3 * NH * NE * NHS) / 256, 256, 0, stream>>>(Wq, Wk, Wv, WqkvT);
        convT_kernel<<<dim3((NE * NE + 255) / 256, NL), 256, 0, stream>>>(Wproj, WprojT, NE, NE);
        convT_kernel<<<dim3((NE * 4 * NE + 255) / 256, NL), 256, 0, stream>>>(W1, W1T, NE, 4 * NE);
        convT_kernel<<<dim3((NE * 4 * NE + 255) / 256, NL), 256, 0, stream>>>(W2, W2T, 4 * NE, NE);
        convLM_kernel<<<(80 * NE + 255) / 256, 256, 0, stream>>>(Wlm, WlmT);
    }

    const int gLN = NM / 4;
    const int nbm = NM / 128;
    for (int l = 0; l < NL; ++l) {
        ln_kernel<<<gLN, 256, 0, stream>>>(x, ln1_g + l * NE, ln1_b + l * NE, h);
        if (fast) {
            gemm_qkv_f<<<nbm * (3 * NE / 128), 256, 0, stream>>>(
                h, WqkvT + (size_t)l * 3 * NE * NE, qb, kb, vb);
        } else {
            const size_t wqkv = (size_t)l * NH * NE * NHS;
            gemm_qkv_kernel<<<nbm * (3 * NE / 64), 256, 0, stream>>>(
                h, Wq + wqkv, Wk + wqkv, Wv + wqkv, qb, kb, vb);
        }
        attn_kernel<<<NB * NH, 256, 0, stream>>>(qb, kb, vb, ob);
        if (fast) {
            gemm_resid_f<<<nbm * (NE / 128), 256, 0, stream>>>(
                ob, WprojT + (size_t)l * NE * NE, NE, NE, bproj + l * NE, x);
        } else {
            gemm_resid_kernel<<<nbm * (NE / 64), 256, 0, stream>>>(
                ob, Wproj + (size_t)l * NE * NE, NE, NE, bproj + l * NE, x);
        }
        ln_kernel<<<gLN, 256, 0, stream>>>(x, ln2_g + l * NE, ln2_b + l * NE, h);
        if (fast) {
            gemm_relu_f<<<nbm * (4 * NE / 128), 256, 0, stream>>>(
                h, W1T + (size_t)l * NE * 4 * NE, 4 * NE, NE, b1 + l * 4 * NE, ub);
            gemm_resid_f<<<nbm * (NE / 128), 256, 0, stream>>>(
                ub, W2T + (size_t)l * NE * 4 * NE, NE, 4 * NE, b2 + l * NE, x);
        } else {
            gemm_relu_kernel<<<nbm * (4 * NE / 64), 256, 0, stream>>>(
                h, W1 + (size_t)l * NE * 4 * NE, 4 * NE, NE, b1 + l * 4 * NE, ub);
            gemm_resid_kernel<<<nbm * (NE / 64), 256, 0, stream>>>(
                ub, W2 + (size_t)l * NE * 4 * NE, NE, 4 * NE, b2 + l * NE, x);
        }
    }

    ln_kernel<<<gLN, 256, 0, stream>>>(x, lnf_g, lnf_b, h);
    if (fast)
        lmhead_f<<<NM / 64, 256, 0, stream>>>(h, WlmT, blm, out);
    else
        lmhead_kernel<<<(NM * NV) / 256, 256, 0, stream>>>(h, Wlm, blm, out);
    loss_kernel<<<NM / 256, 256, 0, stream>>>(out, targets, lossacc);
    if (out_size > NM * NV)
        loss_final_kernel<<<1, 1, 0, stream>>>(lossacc, out + (size_t)NM * NV);
}

// Round 11
// 1212.744 us; speedup vs baseline: 10.1290x; 1.0918x over previous
//
#include <hip/hip_runtime.h>
#include <hip/hip_bf16.h>

typedef unsigned short u16;
typedef __attribute__((ext_vector_type(8))) unsigned short us8;
typedef __attribute__((ext_vector_type(8))) short mfma_in8;   // 8 bf16 in 4 VGPRs
typedef __attribute__((ext_vector_type(4))) float f32x4;

#define NL 6
#define NH 6
#define NE 384
#define NHS 64
#define NT 256
#define NB 64
#define NV 65
#define NM (NB * NT)          // 16384 tokens
#define SCALE 0.051031036307982884f   // 384^-0.5
#define VTP 264               // V^T LDS row stride (u16)
#define PSP 44                // P-tile LDS row stride (u16)

static __device__ __forceinline__ float bf2f(u16 u) {
    return __uint_as_float(((unsigned int)u) << 16);
}
static __device__ __forceinline__ u16 f2bf(float f) {
    unsigned int x = __float_as_uint(f);
    unsigned int r = x + 0x7fffu + ((x >> 16) & 1u);   // RNE
    return (u16)(r >> 16);
}
static __device__ __forceinline__ void llds16(const u16* g, u16* l) {
    __builtin_amdgcn_global_load_lds(
        (const __attribute__((address_space(1))) void*)g,
        (__attribute__((address_space(3))) void*)l, 16, 0, 0);
}

// ---------------- embedding: x(bf16) = tok_emb[idx] + pos_emb --------------------
__global__ __launch_bounds__(256)
void embed_kernel(const int* __restrict__ idx, const float* __restrict__ tok,
                  const float* __restrict__ pos, u16* __restrict__ x) {
    int gid = blockIdx.x * 256 + threadIdx.x;          // over NM*NE
    int bt = gid / NE, e = gid % NE;
    int t = bt & (NT - 1);
    x[gid] = f2bf(tok[idx[bt] * NE + e] + pos[t * NE + e]);
}

// ---------------- LayerNorm: bf16 x -> bf16 out; 16 lanes/token, us8 vector IO ---
__global__ __launch_bounds__(256)
void ln_kernel(const u16* __restrict__ x, const float* __restrict__ g,
               const float* __restrict__ b, u16* __restrict__ out) {
    const int sub = threadIdx.x & 15;                  // lane within token group
    const int token = blockIdx.x * 16 + (threadIdx.x >> 4);
    const u16* row = x + (size_t)token * NE + sub * 24;
    us8 v0 = *(const us8*)row;
    us8 v1 = *(const us8*)(row + 8);
    us8 v2 = *(const us8*)(row + 16);
    float vals[24];
#pragma unroll
    for (int j = 0; j < 8; ++j) {
        vals[j] = bf2f(v0[j]); vals[8 + j] = bf2f(v1[j]); vals[16 + j] = bf2f(v2[j]);
    }
    float s = 0.f;
#pragma unroll
    for (int j = 0; j < 24; ++j) s += vals[j];
#pragma unroll
    for (int off = 8; off >= 1; off >>= 1) s += __shfl_xor(s, off);
    float mean = s * (1.f / NE);
    float s2 = 0.f;
#pragma unroll
    for (int j = 0; j < 24; ++j) { float d = vals[j] - mean; s2 += d * d; }
#pragma unroll
    for (int off = 8; off >= 1; off >>= 1) s2 += __shfl_xor(s2, off);
    float inv = rsqrtf(s2 * (1.f / NE) + 1e-5f);
    const float* gp = g + sub * 24;
    const float* bp = b + sub * 24;
    us8 o0, o1, o2;
#pragma unroll
    for (int j = 0; j < 8; ++j) {
        o0[j] = f2bf((vals[j] - mean) * inv * gp[j] + bp[j]);
        o1[j] = f2bf((vals[8 + j] - mean) * inv * gp[8 + j] + bp[8 + j]);
        o2[j] = f2bf((vals[16 + j] - mean) * inv * gp[16 + j] + bp[16 + j]);
    }
    u16* orow = out + (size_t)token * NE + sub * 24;
    *(us8*)orow = o0;
    *(us8*)(orow + 8) = o1;
    *(us8*)(orow + 16) = o2;
}

// ---------------- weight conversion -----------------------------------------------
__global__ __launch_bounds__(256)
void convQKV_kernel(const float* __restrict__ Wq, const float* __restrict__ Wk,
                    const float* __restrict__ Wv, u16* __restrict__ dst) {
    int i = blockIdx.x * 256 + threadIdx.x;            // over NL*3*NH*NE*NHS
    int s = i & 63; int rest = i >> 6;
    int e = rest % NE; rest /= NE;
    int hh = rest % NH; rest /= NH;
    int which = rest % 3; int l = rest / 3;
    const float* W = which == 0 ? Wq : which == 1 ? Wk : Wv;
    float v = W[((size_t)(l * NH + hh) * NE + e) * NHS + s];
    dst[((size_t)l * 3 * NE + which * NE + hh * NHS + s) * NE + e] = f2bf(v);
}
__global__ __launch_bounds__(256)
void convT_kernel(const float* __restrict__ src, u16* __restrict__ dst,
                  int K, int N) {
    const float* s = src + (size_t)blockIdx.y * K * N;
    u16* d = dst + (size_t)blockIdx.y * K * N;
    int i = blockIdx.x * 256 + threadIdx.x;
    if (i >= K * N) return;
    int k = i / N, n = i % N;
    d[(size_t)n * K + k] = f2bf(s[i]);
}
__global__ __launch_bounds__(256)
void convLM_kernel(const float* __restrict__ Wlm, u16* __restrict__ dst) {
    int i = blockIdx.x * 256 + threadIdx.x;            // over 80*NE
    if (i >= 80 * NE) return;
    int n = i / NE, k = i % NE;
    dst[i] = f2bf(n < NV ? Wlm[(size_t)k * NV + n] : 0.f);
}

// ---------------- 128x128 MFMA core (qkv / relu) ---------------------------------
static __device__ __forceinline__ void gemm128_core(
        const u16* __restrict__ A, const u16* __restrict__ BT,
        int m0, int n0, int K, f32x4 acc[4][4]) {
    __shared__ __align__(16) u16 smA[128 * 32];
    __shared__ __align__(16) u16 smB[128 * 32];
    const int tid = threadIdx.x;
    const int wv = tid >> 6, lane = tid & 63;
    const int wm = wv & 1, wn = wv >> 1;
    const int quad = lane >> 4, l16 = lane & 15;
    for (int k0 = 0; k0 < K; k0 += 32) {
        __syncthreads();
#pragma unroll
        for (int j = 0; j < 2; ++j) {
            int c = tid + j * 256;
            llds16(A + (size_t)(m0 + (c >> 2)) * K + k0 + ((c & 3) << 3), smA + c * 8);
            llds16(BT + (size_t)(n0 + (c >> 2)) * K + k0 + ((c & 3) << 3), smB + c * 8);
        }
        __syncthreads();
        mfma_in8 af[4], bf[4];
#pragma unroll
        for (int im = 0; im < 4; ++im)
            af[im] = *(const mfma_in8*)&smA[(wm * 64 + im * 16 + l16) * 32 + quad * 8];
#pragma unroll
        for (int in = 0; in < 4; ++in)
            bf[in] = *(const mfma_in8*)&smB[(wn * 64 + in * 16 + l16) * 32 + quad * 8];
#pragma unroll
        for (int im = 0; im < 4; ++im)
#pragma unroll
            for (int in = 0; in < 4; ++in)
                acc[im][in] = __builtin_amdgcn_mfma_f32_16x16x32_bf16(
                    af[im], bf[in], acc[im][in], 0, 0, 0);
    }
}

__global__ __launch_bounds__(256)
void gemm_qkv_f(const u16* __restrict__ A, const u16* __restrict__ BT,
                u16* __restrict__ qout, u16* __restrict__ kout,
                u16* __restrict__ vout) {
    const int nbm = NM >> 7;
    const int bm = blockIdx.x % nbm, bn = blockIdx.x / nbm;
    const int m0 = bm << 7, n0 = bn << 7;              // N=1152
    f32x4 acc[4][4] = {};
    gemm128_core(A, BT, m0, n0, NE, acc);
    const int lane = threadIdx.x & 63, wv = threadIdx.x >> 6;
    const int wm = wv & 1, wn = wv >> 1;
    const int quad = lane >> 4, l16 = lane & 15;
#pragma unroll
    for (int im = 0; im < 4; ++im)
#pragma unroll
        for (int in = 0; in < 4; ++in)
#pragma unroll
            for (int r = 0; r < 4; ++r) {
                int row = m0 + wm * 64 + im * 16 + quad * 4 + r;
                int col = n0 + wn * 64 + in * 16 + l16;
                int which = col / NE, j = col % NE;
                int hh = j >> 6, s = j & 63;
                int bb = row >> 8, tt = row & 255;
                u16* dst = (which == 0) ? qout : (which == 1) ? kout : vout;
                dst[((((size_t)bb * NH + hh) << 8) + tt) * NHS + s] =
                    f2bf(acc[im][in][r]);
            }
}

__global__ __launch_bounds__(256)
void gemm_relu_f(const u16* __restrict__ A, const u16* __restrict__ BT,
                 const int N, const int K,
                 const float* __restrict__ bias, u16* __restrict__ outb) {
    const int nbm = NM >> 7;
    const int bm = blockIdx.x % nbm, bn = blockIdx.x / nbm;
    const int m0 = bm << 7, n0 = bn << 7;
    f32x4 acc[4][4] = {};
    gemm128_core(A, BT, m0, n0, K, acc);
    const int lane = threadIdx.x & 63, wv = threadIdx.x >> 6;
    const int wm = wv & 1, wn = wv >> 1;
    const int quad = lane >> 4, l16 = lane & 15;
#pragma unroll
    for (int im = 0; im < 4; ++im)
#pragma unroll
        for (int in = 0; in < 4; ++in)
#pragma unroll
            for (int r = 0; r < 4; ++r) {
                int row = m0 + wm * 64 + im * 16 + quad * 4 + r;
                int col = n0 + wn * 64 + in * 16 + l16;
                outb[(size_t)row * N + col] =
                    f2bf(fmaxf(acc[im][in][r] + bias[col], 0.f));
            }
}

// ---------------- 128x64 MFMA core for resid GEMMs (more blocks, bf16 RMW) -------
static __device__ __forceinline__ void gemm64_core(
        const u16* __restrict__ A, const u16* __restrict__ BT,
        int m0, int n0, int K, f32x4 acc[4][2]) {
    __shared__ __align__(16) u16 smA[128 * 32];
    __shared__ __align__(16) u16 smB[64 * 32];
    const int tid = threadIdx.x;
    const int wv = tid >> 6, lane = tid & 63;
    const int wm = wv & 1, wn = wv >> 1;
    const int quad = lane >> 4, l16 = lane & 15;
    for (int k0 = 0; k0 < K; k0 += 32) {
        __syncthreads();
        llds16(A + (size_t)(m0 + (tid >> 2)) * K + k0 + ((tid & 3) << 3), smA + tid * 8);
        llds16(A + (size_t)(m0 + 64 + (tid >> 2)) * K + k0 + ((tid & 3) << 3),
               smA + (tid + 256) * 8);
        llds16(BT + (size_t)(n0 + (tid >> 2)) * K + k0 + ((tid & 3) << 3), smB + tid * 8);
        __syncthreads();
        mfma_in8 af[4], bf[2];
#pragma unroll
        for (int im = 0; im < 4; ++im)
            af[im] = *(const mfma_in8*)&smA[(wm * 64 + im * 16 + l16) * 32 + quad * 8];
#pragma unroll
        for (int in = 0; in < 2; ++in)
            bf[in] = *(const mfma_in8*)&smB[(wn * 32 + in * 16 + l16) * 32 + quad * 8];
#pragma unroll
        for (int im = 0; im < 4; ++im)
#pragma unroll
            for (int in = 0; in < 2; ++in)
                acc[im][in] = __builtin_amdgcn_mfma_f32_16x16x32_bf16(
                    af[im], bf[in], acc[im][in], 0, 0, 0);
    }
}

__global__ __launch_bounds__(256)
void gemm_resid_f(const u16* __restrict__ A, const u16* __restrict__ BT,
                  const int N, const int K,
                  const float* __restrict__ bias, u16* __restrict__ resid) {
    const int nbm = NM >> 7;
    const int bm = blockIdx.x % nbm, bn = blockIdx.x / nbm;
    const int m0 = bm << 7, n0 = bn << 6;
    f32x4 acc[4][2] = {};
    gemm64_core(A, BT, m0, n0, K, acc);
    const int lane = threadIdx.x & 63, wv = threadIdx.x >> 6;
    const int wm = wv & 1, wn = wv >> 1;
    const int quad = lane >> 4, l16 = lane & 15;
#pragma unroll
    for (int im = 0; im < 4; ++im)
#pragma unroll
        for (int in = 0; in < 2; ++in)
#pragma unroll
            for (int r = 0; r < 4; ++r) {
                int row = m0 + wm * 64 + im * 16 + quad * 4 + r;
                int col = n0 + wn * 32 + in * 16 + l16;
                size_t o = (size_t)row * N + col;
                resid[o] = f2bf(bf2f(resid[o]) + acc[im][in][r] + bias[col]);
            }
}

// ---------------- fast lmhead ----------------------------------------------------
__global__ __launch_bounds__(256)
void lmhead_f(const u16* __restrict__ xf, const u16* __restrict__ WlmT,
              const float* __restrict__ blm, float* __restrict__ out) {
    const int w = threadIdx.x >> 6, lane = threadIdx.x & 63;
    const int quad = lane >> 4, l16 = lane & 15;
    const int m0 = (blockIdx.x * 4 + w) * 16;
    f32x4 acc[5] = {};
#pragma unroll 2
    for (int k0 = 0; k0 < NE; k0 += 32) {
        mfma_in8 a = *(const mfma_in8*)(xf + (size_t)(m0 + l16) * NE + k0 + quad * 8);
#pragma unroll
        for (int nt = 0; nt < 5; ++nt) {
            mfma_in8 b = *(const mfma_in8*)(WlmT + (size_t)(nt * 16 + l16) * NE + k0 + quad * 8);
            acc[nt] = __builtin_amdgcn_mfma_f32_16x16x32_bf16(a, b, acc[nt], 0, 0, 0);
        }
    }
#pragma unroll
    for (int nt = 0; nt < 5; ++nt) {
        int col = nt * 16 + l16;
        if (col < NV) {
            float bb = blm[col];
#pragma unroll
            for (int r = 0; r < 4; ++r)
                out[(size_t)(m0 + quad * 4 + r) * NV + col] = acc[nt][r] + bb;
        }
    }
}

// ---------------- MFMA flash attention (unchanged) --------------------------------
static __device__ __forceinline__ f32x4 shflx4(f32x4 v, int off) {
    f32x4 r;
#pragma unroll
    for (int i = 0; i < 4; ++i) r[i] = __shfl_xor(v[i], off);
    return r;
}
__global__ __launch_bounds__(256)
void attn_kernel(const u16* __restrict__ q, const u16* __restrict__ k,
                 const u16* __restrict__ v, u16* __restrict__ o) {
    __shared__ __align__(16) u16 sVt[64 * VTP];
    __shared__ __align__(16) u16 sP[4][16 * PSP];
    const int tid = threadIdx.x;
    const int bh = blockIdx.x;
    const int b = bh / NH, hh = bh % NH;
    const size_t base = (size_t)bh << 14;
    {
        const us8* vg = (const us8*)(v + base);
        const int t0 = tid >> 3, c8 = tid & 7;
#pragma unroll
        for (int i = 0; i < 8; ++i) {
            int tt = t0 + i * 32;
            us8 vv = vg[tt * 8 + c8];
#pragma unroll
            for (int j = 0; j < 8; ++j)
                sVt[(c8 * 8 + j) * VTP + tt] = vv[j];
        }
    }
    __syncthreads();
    const int w = tid >> 6, lane = tid & 63;
    const int quad = lane >> 4, l16 = lane & 15;
    mfma_in8 aq[4][2];
#pragma unroll
    for (int mt = 0; mt < 4; ++mt) {
        const int t = w + 4 * mt;
        const u16* qp = q + base + (size_t)(16 * t + l16) * NHS + quad * 8;
        aq[mt][0] = *(const mfma_in8*)qp;
        aq[mt][1] = *(const mfma_in8*)(qp + 32);
    }
    f32x4 oa[4][4] = {};
    f32x4 lsum[4] = {};
    const f32x4 zero = {};
    const int jmax = ((w + 12) >> 1) + 1;
    for (int j = 0; j < jmax; ++j) {
        mfma_in8 bv[4];
#pragma unroll
        for (int nt = 0; nt < 4; ++nt)
            bv[nt] = *(const mfma_in8*)&sVt[(nt * 16 + l16) * VTP + j * 32 + quad * 8];
        mfma_in8 bk[2][2];
#pragma unroll
        for (int nt = 0; nt < 2; ++nt) {
            const u16* kp = k + base + (size_t)(j * 32 + nt * 16 + l16) * NHS + quad * 8;
            bk[nt][0] = *(const mfma_in8*)kp;
            bk[nt][1] = *(const mfma_in8*)(kp + 32);
        }
#pragma unroll
        for (int mt = 0; mt < 4; ++mt) {
            const int t = w + 4 * mt;
            const int jm = t >> 1;
            if (j > jm) continue;
            f32x4 s0 = __builtin_amdgcn_mfma_f32_16x16x32_bf16(aq[mt][0], bk[0][0], zero, 0, 0, 0);
            s0 = __builtin_amdgcn_mfma_f32_16x16x32_bf16(aq[mt][1], bk[0][1], s0, 0, 0, 0);
            f32x4 s1 = __builtin_amdgcn_mfma_f32_16x16x32_bf16(aq[mt][0], bk[1][0], zero, 0, 0, 0);
            s1 = __builtin_amdgcn_mfma_f32_16x16x32_bf16(aq[mt][1], bk[1][1], s1, 0, 0, 0);
            float p[2][4];
            const bool boundary = (j == jm);
#pragma unroll
            for (int nt = 0; nt < 2; ++nt)
#pragma unroll
                for (int r = 0; r < 4; ++r) {
                    float sv = (nt ? s1[r] : s0[r]) * SCALE;
                    float e = __expf(sv);
                    if (boundary) {
                        int u = j * 32 + nt * 16 + l16;
                        int R = 16 * t + quad * 4 + r;
                        if (u > R) e = 0.f;
                    }
                    p[nt][r] = e;
                }
            f32x4 rs;
#pragma unroll
            for (int r = 0; r < 4; ++r) rs[r] = p[0][r] + p[1][r];
            rs += shflx4(rs, 1);
            rs += shflx4(rs, 2);
            rs += shflx4(rs, 4);
            rs += shflx4(rs, 8);
            lsum[mt] += rs;
#pragma unroll
            for (int nt = 0; nt < 2; ++nt)
#pragma unroll
                for (int r = 0; r < 4; ++r)
                    sP[w][(quad * 4 + r) * PSP + nt * 16 + l16] = f2bf(p[nt][r]);
            mfma_in8 ap = *(const mfma_in8*)&sP[w][l16 * PSP + quad * 8];
#pragma unroll
            for (int nt = 0; nt < 4; ++nt)
                oa[mt][nt] = __builtin_amdgcn_mfma_f32_16x16x32_bf16(ap, bv[nt], oa[mt][nt], 0, 0, 0);
        }
    }
#pragma unroll
    for (int mt = 0; mt < 4; ++mt) {
        const int t = w + 4 * mt;
        f32x4 inv;
#pragma unroll
        for (int r = 0; r < 4; ++r) inv[r] = 1.f / lsum[mt][r];
#pragma unroll
        for (int nt = 0; nt < 4; ++nt)
#pragma unroll
            for (int r = 0; r < 4; ++r) {
                int row = 16 * t + quad * 4 + r;
                int col = hh * NHS + nt * 16 + l16;
                o[((size_t)(b * NT + row)) * NE + col] = f2bf(oa[mt][nt][r] * inv[r]);
            }
    }
}

// ---------------- loss ------------------------------------------------------------
__global__ __launch_bounds__(256)
void loss_kernel(const float* __restrict__ logits, const int* __restrict__ targets,
                 float* __restrict__ acc) {
    int t = blockIdx.x * 256 + threadIdx.x;
    const float* row = logits + (size_t)t * NV;
    float mx = -1e30f;
    for (int i = 0; i < NV; ++i) mx = fmaxf(mx, row[i]);
    float se = 0.f;
    for (int i = 0; i < NV; ++i) se += __expf(row[i] - mx);
    float li = __logf(se) + mx - row[targets[t]];
#pragma unroll
    for (int off = 32; off >= 1; off >>= 1) li += __shfl_xor(li, off);
    if ((threadIdx.x & 63) == 0) atomicAdd(acc, li);
}
__global__ void loss_final_kernel(const float* __restrict__ acc, float* __restrict__ out) {
    out[0] = acc[0] * (1.f / (float)NM);
}
__global__ void code_kernel(float* __restrict__ out0, float code) {
    if (threadIdx.x == 0 && blockIdx.x == 0) out0[0] = code;
}

// ================================ host ==========================================
extern "C" void kernel_launch(void* const* d_in, const int* in_sizes, int n_in,
                              void* d_out, int out_size, void* d_ws, size_t ws_size,
                              hipStream_t stream) {
    const int*   idx      = (const int*)d_in[0];
    const int*   targets  = (const int*)d_in[1];
    const float* tok_emb  = (const float*)d_in[2];
    const float* pos_emb  = (const float*)d_in[3];
    const float* Wq       = (const float*)d_in[4];
    const float* Wk       = (const float*)d_in[5];
    const float* Wv       = (const float*)d_in[6];
    const float* Wproj    = (const float*)d_in[7];
    const float* bproj    = (const float*)d_in[8];
    const float* ln1_g    = (const float*)d_in[9];
    const float* ln1_b    = (const float*)d_in[10];
    const float* ln2_g    = (const float*)d_in[11];
    const float* ln2_b    = (const float*)d_in[12];
    const float* W1       = (const float*)d_in[13];
    const float* b1       = (const float*)d_in[14];
    const float* W2       = (const float*)d_in[15];
    const float* b2       = (const float*)d_in[16];
    const float* lnf_g    = (const float*)d_in[17];
    const float* lnf_b    = (const float*)d_in[18];
    const float* Wlm      = (const float*)d_in[19];
    const float* blm      = (const float*)d_in[20];
    float* out = (float*)d_out;

    static const int expect[21] = {
        16384, 16384, 24960, 98304, 884736, 884736, 884736, 884736, 2304,
        2304, 2304, 2304, 2304, 3538944, 9216, 3538944, 2304, 384, 384,
        24960, 65};
    if (n_in < 21) { code_kernel<<<1, 1, 0, stream>>>(out, 990.f); return; }
    for (int i = 0; i < 21; ++i)
        if (in_sizes[i] != expect[i]) {
            code_kernel<<<1, 1, 0, stream>>>(out, 1000.f + 10.f * i);
            return;
        }

    // ---- workspace layout (~97 MB) ----
    char* ws = (char*)d_ws;
    size_t off = 0;
    auto alloc = [&](size_t bytes) -> void* {
        void* p = ws + off;
        off += (bytes + 255) & ~(size_t)255;
        return p;
    };
    const size_t S = (size_t)NM * NE * 2;          // 12.58 MB
    float* lossacc = (float*)alloc(256);
    u16*   x       = (u16*)alloc(S);               // bf16 residual master
    u16*   h       = (u16*)alloc(S);
    u16*   region  = (u16*)alloc(4 * S);           // q|k|v|o, overlaid by ub
    u16*   qb = region;
    u16*   kb = region + NM * NE;
    u16*   vb = region + 2 * (size_t)NM * NE;
    u16*   ob = region + 3 * (size_t)NM * NE;
    u16*   ub = region;
    u16* WqkvT  = (u16*)alloc((size_t)NL * 3 * NE * NE * 2);
    u16* WprojT = (u16*)alloc((size_t)NL * NE * NE * 2);
    u16* W1T    = (u16*)alloc((size_t)NL * NE * 4 * NE * 2);
    u16* W2T    = (u16*)alloc((size_t)NL * NE * 4 * NE * 2);
    u16* WlmT   = (u16*)alloc((size_t)80 * NE * 2);

    if (ws_size < off) { code_kernel<<<1, 1, 0, stream>>>(out, 999.f); return; }

    hipMemsetAsync(lossacc, 0, 4, stream);
    embed_kernel<<<(NM * NE) / 256, 256, 0, stream>>>(idx, tok_emb, pos_emb, x);

    convQKV_kernel<<<(NL * 3 * NH * NE * NHS) / 256, 256, 0, stream>>>(Wq, Wk, Wv, WqkvT);
    convT_kernel<<<dim3((NE * NE + 255) / 256, NL), 256, 0, stream>>>(Wproj, WprojT, NE, NE);
    convT_kernel<<<dim3((NE * 4 * NE + 255) / 256, NL), 256, 0, stream>>>(W1, W1T, NE, 4 * NE);
    convT_kernel<<<dim3((NE * 4 * NE + 255) / 256, NL), 256, 0, stream>>>(W2, W2T, 4 * NE, NE);
    convLM_kernel<<<(80 * NE + 255) / 256, 256, 0, stream>>>(Wlm, WlmT);

    const int gLN = NM / 16;
    const int nbm = NM / 128;
    for (int l = 0; l < NL; ++l) {
        ln_kernel<<<gLN, 256, 0, stream>>>(x, ln1_g + l * NE, ln1_b + l * NE, h);
        gemm_qkv_f<<<nbm * (3 * NE / 128), 256, 0, stream>>>(
            h, WqkvT + (size_t)l * 3 * NE * NE, qb, kb, vb);
        attn_kernel<<<NB * NH, 256, 0, stream>>>(qb, kb, vb, ob);
        gemm_resid_f<<<nbm * (NE / 64), 256, 0, stream>>>(
            ob, WprojT + (size_t)l * NE * NE, NE, NE, bproj + l * NE, x);
        ln_kernel<<<gLN, 256, 0, stream>>>(x, ln2_g + l * NE, ln2_b + l * NE, h);
        gemm_relu_f<<<nbm * (4 * NE / 128), 256, 0, stream>>>(
            h, W1T + (size_t)l * NE * 4 * NE, 4 * NE, NE, b1 + l * 4 * NE, ub);
        gemm_resid_f<<<nbm * (NE / 64), 256, 0, stream>>>(
            ub, W2T + (size_t)l * NE * 4 * NE, NE, 4 * NE, b2 + l * NE, x);
    }

    ln_kernel<<<gLN, 256, 0, stream>>>(x, lnf_g, lnf_b, h);
    lmhead_f<<<NM / 64, 256, 0, stream>>>(h, WlmT, blm, out);
    loss_kernel<<<NM / 256, 256, 0, stream>>>(out, targets, lossacc);
    if (out_size > NM * NV)
        loss_final_kernel<<<1, 1, 0, stream>>>(lossacc, out + (size_t)NM * NV);
}

// Round 12
// 1151.698 us; speedup vs baseline: 10.6659x; 1.0530x over previous
//
#include <hip/hip_runtime.h>
#include <hip/hip_bf16.h>

typedef unsigned short u16;
typedef __attribute__((ext_vector_type(8))) unsigned short us8;
typedef __attribute__((ext_vector_type(8))) short mfma_in8;   // 8 bf16 in 4 VGPRs
typedef __attribute__((ext_vector_type(4))) float f32x4;

#define NL 6
#define NH 6
#define NE 384
#define NHS 64
#define NT 256
#define NB 64
#define NV 65
#define NM (NB * NT)          // 16384 tokens
#define SCALE 0.051031036307982884f   // 384^-0.5
#define VTP 264               // V^T LDS row stride (u16)
#define PSP 44                // P-tile LDS row stride (u16)

static __device__ __forceinline__ float bf2f(u16 u) {
    return __uint_as_float(((unsigned int)u) << 16);
}
static __device__ __forceinline__ u16 f2bf(float f) {
    unsigned int x = __float_as_uint(f);
    unsigned int r = x + 0x7fffu + ((x >> 16) & 1u);   // RNE
    return (u16)(r >> 16);
}
static __device__ __forceinline__ void llds16(const u16* g, u16* l) {
    __builtin_amdgcn_global_load_lds(
        (const __attribute__((address_space(1))) void*)g,
        (__attribute__((address_space(3))) void*)l, 16, 0, 0);
}

// ---------------- embedding: x(bf16) = tok_emb[idx] + pos_emb --------------------
__global__ __launch_bounds__(256)
void embed_kernel(const int* __restrict__ idx, const float* __restrict__ tok,
                  const float* __restrict__ pos, u16* __restrict__ x) {
    int gid = blockIdx.x * 256 + threadIdx.x;          // over NM*NE
    int bt = gid / NE, e = gid % NE;
    int t = bt & (NT - 1);
    x[gid] = f2bf(tok[idx[bt] * NE + e] + pos[t * NE + e]);
}

// ---------------- LayerNorm: bf16 x -> bf16 out; 16 lanes/token ------------------
__global__ __launch_bounds__(256)
void ln_kernel(const u16* __restrict__ x, const float* __restrict__ g,
               const float* __restrict__ b, u16* __restrict__ out) {
    const int sub = threadIdx.x & 15;
    const int token = blockIdx.x * 16 + (threadIdx.x >> 4);
    const u16* row = x + (size_t)token * NE + sub * 24;
    us8 v0 = *(const us8*)row;
    us8 v1 = *(const us8*)(row + 8);
    us8 v2 = *(const us8*)(row + 16);
    float vals[24];
#pragma unroll
    for (int j = 0; j < 8; ++j) {
        vals[j] = bf2f(v0[j]); vals[8 + j] = bf2f(v1[j]); vals[16 + j] = bf2f(v2[j]);
    }
    float s = 0.f;
#pragma unroll
    for (int j = 0; j < 24; ++j) s += vals[j];
#pragma unroll
    for (int off = 8; off >= 1; off >>= 1) s += __shfl_xor(s, off);
    float mean = s * (1.f / NE);
    float s2 = 0.f;
#pragma unroll
    for (int j = 0; j < 24; ++j) { float d = vals[j] - mean; s2 += d * d; }
#pragma unroll
    for (int off = 8; off >= 1; off >>= 1) s2 += __shfl_xor(s2, off);
    float inv = rsqrtf(s2 * (1.f / NE) + 1e-5f);
    const float* gp = g + sub * 24;
    const float* bp = b + sub * 24;
    us8 o0, o1, o2;
#pragma unroll
    for (int j = 0; j < 8; ++j) {
        o0[j] = f2bf((vals[j] - mean) * inv * gp[j] + bp[j]);
        o1[j] = f2bf((vals[8 + j] - mean) * inv * gp[8 + j] + bp[8 + j]);
        o2[j] = f2bf((vals[16 + j] - mean) * inv * gp[16 + j] + bp[16 + j]);
    }
    u16* orow = out + (size_t)token * NE + sub * 24;
    *(us8*)orow = o0;
    *(us8*)(orow + 8) = o1;
    *(us8*)(orow + 16) = o2;
}

// ---------------- weight conversion -----------------------------------------------
__global__ __launch_bounds__(256)
void convQKV_kernel(const float* __restrict__ Wq, const float* __restrict__ Wk,
                    const float* __restrict__ Wv, u16* __restrict__ dst) {
    int i = blockIdx.x * 256 + threadIdx.x;            // over NL*3*NH*NE*NHS
    int s = i & 63; int rest = i >> 6;
    int e = rest % NE; rest /= NE;
    int hh = rest % NH; rest /= NH;
    int which = rest % 3; int l = rest / 3;
    const float* W = which == 0 ? Wq : which == 1 ? Wk : Wv;
    float v = W[((size_t)(l * NH + hh) * NE + e) * NHS + s];
    dst[((size_t)l * 3 * NE + which * NE + hh * NHS + s) * NE + e] = f2bf(v);
}
__global__ __launch_bounds__(256)
void convT_kernel(const float* __restrict__ src, u16* __restrict__ dst,
                  int K, int N) {
    const float* s = src + (size_t)blockIdx.y * K * N;
    u16* d = dst + (size_t)blockIdx.y * K * N;
    int i = blockIdx.x * 256 + threadIdx.x;
    if (i >= K * N) return;
    int k = i / N, n = i % N;
    d[(size_t)n * K + k] = f2bf(s[i]);
}
__global__ __launch_bounds__(256)
void convLM_kernel(const float* __restrict__ Wlm, u16* __restrict__ dst) {
    int i = blockIdx.x * 256 + threadIdx.x;            // over 80*NE
    if (i >= 80 * NE) return;
    int n = i / NE, k = i % NE;
    dst[i] = f2bf(n < NV ? Wlm[(size_t)k * NV + n] : 0.f);
}

// ---------------- 128x128 MFMA core, double-buffered LDS pipeline ----------------
static __device__ __forceinline__ void gemm128_core(
        const u16* __restrict__ A, const u16* __restrict__ BT,
        int m0, int n0, int K, f32x4 acc[4][4]) {
    __shared__ __align__(16) u16 smA[2][128 * 32];
    __shared__ __align__(16) u16 smB[2][128 * 32];
    const int tid = threadIdx.x;
    const int wv = tid >> 6, lane = tid & 63;
    const int wm = wv & 1, wn = wv >> 1;
    const int quad = lane >> 4, l16 = lane & 15;
    const int c0 = tid, c1 = tid + 256;
    const size_t aoff0 = (size_t)(m0 + (c0 >> 2)) * K + ((c0 & 3) << 3);
    const size_t aoff1 = (size_t)(m0 + (c1 >> 2)) * K + ((c1 & 3) << 3);
    const size_t boff0 = (size_t)(n0 + (c0 >> 2)) * K + ((c0 & 3) << 3);
    const size_t boff1 = (size_t)(n0 + (c1 >> 2)) * K + ((c1 & 3) << 3);
    // preload tile 0
    llds16(A + aoff0, smA[0] + c0 * 8);
    llds16(A + aoff1, smA[0] + c1 * 8);
    llds16(BT + boff0, smB[0] + c0 * 8);
    llds16(BT + boff1, smB[0] + c1 * 8);
    __syncthreads();
    const int nk = K >> 5;
    for (int ki = 0; ki < nk; ++ki) {
        const int cur = ki & 1, nxt = cur ^ 1;
        if (ki + 1 < nk) {
            const int k0 = (ki + 1) << 5;
            llds16(A + aoff0 + k0, smA[nxt] + c0 * 8);
            llds16(A + aoff1 + k0, smA[nxt] + c1 * 8);
            llds16(BT + boff0 + k0, smB[nxt] + c0 * 8);
            llds16(BT + boff1 + k0, smB[nxt] + c1 * 8);
        }
        mfma_in8 af[4], bf[4];
#pragma unroll
        for (int im = 0; im < 4; ++im)
            af[im] = *(const mfma_in8*)&smA[cur][(wm * 64 + im * 16 + l16) * 32 + quad * 8];
#pragma unroll
        for (int in = 0; in < 4; ++in)
            bf[in] = *(const mfma_in8*)&smB[cur][(wn * 64 + in * 16 + l16) * 32 + quad * 8];
#pragma unroll
        for (int im = 0; im < 4; ++im)
#pragma unroll
            for (int in = 0; in < 4; ++in)
                acc[im][in] = __builtin_amdgcn_mfma_f32_16x16x32_bf16(
                    af[im], bf[in], acc[im][in], 0, 0, 0);
        __syncthreads();   // drains prefetch vmcnt + guards cur-buffer reuse
    }
}

__global__ __launch_bounds__(256)
void gemm_qkv_f(const u16* __restrict__ A, const u16* __restrict__ BT,
                u16* __restrict__ qout, u16* __restrict__ kout,
                u16* __restrict__ vout) {
    const int nbm = NM >> 7;
    const int bm = blockIdx.x % nbm, bn = blockIdx.x / nbm;
    const int m0 = bm << 7, n0 = bn << 7;              // N=1152
    f32x4 acc[4][4] = {};
    gemm128_core(A, BT, m0, n0, NE, acc);
    const int lane = threadIdx.x & 63, wv = threadIdx.x >> 6;
    const int wm = wv & 1, wn = wv >> 1;
    const int quad = lane >> 4, l16 = lane & 15;
#pragma unroll
    for (int im = 0; im < 4; ++im)
#pragma unroll
        for (int in = 0; in < 4; ++in)
#pragma unroll
            for (int r = 0; r < 4; ++r) {
                int row = m0 + wm * 64 + im * 16 + quad * 4 + r;
                int col = n0 + wn * 64 + in * 16 + l16;
                int which = col / NE, j = col % NE;
                int hh = j >> 6, s = j & 63;
                int bb = row >> 8, tt = row & 255;
                u16* dst = (which == 0) ? qout : (which == 1) ? kout : vout;
                dst[((((size_t)bb * NH + hh) << 8) + tt) * NHS + s] =
                    f2bf(acc[im][in][r]);
            }
}

__global__ __launch_bounds__(256)
void gemm_relu_f(const u16* __restrict__ A, const u16* __restrict__ BT,
                 const int N, const int K,
                 const float* __restrict__ bias, u16* __restrict__ outb) {
    const int nbm = NM >> 7;
    const int bm = blockIdx.x % nbm, bn = blockIdx.x / nbm;
    const int m0 = bm << 7, n0 = bn << 7;
    f32x4 acc[4][4] = {};
    gemm128_core(A, BT, m0, n0, K, acc);
    const int lane = threadIdx.x & 63, wv = threadIdx.x >> 6;
    const int wm = wv & 1, wn = wv >> 1;
    const int quad = lane >> 4, l16 = lane & 15;
#pragma unroll
    for (int im = 0; im < 4; ++im)
#pragma unroll
        for (int in = 0; in < 4; ++in)
#pragma unroll
            for (int r = 0; r < 4; ++r) {
                int row = m0 + wm * 64 + im * 16 + quad * 4 + r;
                int col = n0 + wn * 64 + in * 16 + l16;
                outb[(size_t)row * N + col] =
                    f2bf(fmaxf(acc[im][in][r] + bias[col], 0.f));
            }
}

// ---------------- 128x64 MFMA core for resid GEMMs, double-buffered --------------
static __device__ __forceinline__ void gemm64_core(
        const u16* __restrict__ A, const u16* __restrict__ BT,
        int m0, int n0, int K, f32x4 acc[4][2]) {
    __shared__ __align__(16) u16 smA[2][128 * 32];
    __shared__ __align__(16) u16 smB[2][64 * 32];
    const int tid = threadIdx.x;
    const int wv = tid >> 6, lane = tid & 63;
    const int wm = wv & 1, wn = wv >> 1;
    const int quad = lane >> 4, l16 = lane & 15;
    const int c0 = tid, c1 = tid + 256;
    const size_t aoff0 = (size_t)(m0 + (c0 >> 2)) * K + ((c0 & 3) << 3);
    const size_t aoff1 = (size_t)(m0 + (c1 >> 2)) * K + ((c1 & 3) << 3);
    const size_t boff0 = (size_t)(n0 + (c0 >> 2)) * K + ((c0 & 3) << 3);
    llds16(A + aoff0, smA[0] + c0 * 8);
    llds16(A + aoff1, smA[0] + c1 * 8);
    llds16(BT + boff0, smB[0] + c0 * 8);
    __syncthreads();
    const int nk = K >> 5;
    for (int ki = 0; ki < nk; ++ki) {
        const int cur = ki & 1, nxt = cur ^ 1;
        if (ki + 1 < nk) {
            const int k0 = (ki + 1) << 5;
            llds16(A + aoff0 + k0, smA[nxt] + c0 * 8);
            llds16(A + aoff1 + k0, smA[nxt] + c1 * 8);
            llds16(BT + boff0 + k0, smB[nxt] + c0 * 8);
        }
        mfma_in8 af[4], bf[2];
#pragma unroll
        for (int im = 0; im < 4; ++im)
            af[im] = *(const mfma_in8*)&smA[cur][(wm * 64 + im * 16 + l16) * 32 + quad * 8];
#pragma unroll
        for (int in = 0; in < 2; ++in)
            bf[in] = *(const mfma_in8*)&smB[cur][(wn * 32 + in * 16 + l16) * 32 + quad * 8];
#pragma unroll
        for (int im = 0; im < 4; ++im)
#pragma unroll
            for (int in = 0; in < 2; ++in)
                acc[im][in] = __builtin_amdgcn_mfma_f32_16x16x32_bf16(
                    af[im], bf[in], acc[im][in], 0, 0, 0);
        __syncthreads();
    }
}

__global__ __launch_bounds__(256)
void gemm_resid_f(const u16* __restrict__ A, const u16* __restrict__ BT,
                  const int N, const int K,
                  const float* __restrict__ bias, u16* __restrict__ resid) {
    const int nbm = NM >> 7;
    const int bm = blockIdx.x % nbm, bn = blockIdx.x / nbm;
    const int m0 = bm << 7, n0 = bn << 6;
    f32x4 acc[4][2] = {};
    gemm64_core(A, BT, m0, n0, K, acc);
    const int lane = threadIdx.x & 63, wv = threadIdx.x >> 6;
    const int wm = wv & 1, wn = wv >> 1;
    const int quad = lane >> 4, l16 = lane & 15;
#pragma unroll
    for (int im = 0; im < 4; ++im)
#pragma unroll
        for (int in = 0; in < 2; ++in)
#pragma unroll
            for (int r = 0; r < 4; ++r) {
                int row = m0 + wm * 64 + im * 16 + quad * 4 + r;
                int col = n0 + wn * 32 + in * 16 + l16;
                size_t o = (size_t)row * N + col;
                resid[o] = f2bf(bf2f(resid[o]) + acc[im][in][r] + bias[col]);
            }
}

// ---------------- fast lmhead ----------------------------------------------------
__global__ __launch_bounds__(256)
void lmhead_f(const u16* __restrict__ xf, const u16* __restrict__ WlmT,
              const float* __restrict__ blm, float* __restrict__ out) {
    const int w = threadIdx.x >> 6, lane = threadIdx.x & 63;
    const int quad = lane >> 4, l16 = lane & 15;
    const int m0 = (blockIdx.x * 4 + w) * 16;
    f32x4 acc[5] = {};
#pragma unroll 2
    for (int k0 = 0; k0 < NE; k0 += 32) {
        mfma_in8 a = *(const mfma_in8*)(xf + (size_t)(m0 + l16) * NE + k0 + quad * 8);
#pragma unroll
        for (int nt = 0; nt < 5; ++nt) {
            mfma_in8 b = *(const mfma_in8*)(WlmT + (size_t)(nt * 16 + l16) * NE + k0 + quad * 8);
            acc[nt] = __builtin_amdgcn_mfma_f32_16x16x32_bf16(a, b, acc[nt], 0, 0, 0);
        }
    }
#pragma unroll
    for (int nt = 0; nt < 5; ++nt) {
        int col = nt * 16 + l16;
        if (col < NV) {
            float bb = blm[col];
#pragma unroll
            for (int r = 0; r < 4; ++r)
                out[(size_t)(m0 + quad * 4 + r) * NV + col] = acc[nt][r] + bb;
        }
    }
}

// ---------------- MFMA flash attention (unchanged) --------------------------------
static __device__ __forceinline__ f32x4 shflx4(f32x4 v, int off) {
    f32x4 r;
#pragma unroll
    for (int i = 0; i < 4; ++i) r[i] = __shfl_xor(v[i], off);
    return r;
}
__global__ __launch_bounds__(256)
void attn_kernel(const u16* __restrict__ q, const u16* __restrict__ k,
                 const u16* __restrict__ v, u16* __restrict__ o) {
    __shared__ __align__(16) u16 sVt[64 * VTP];
    __shared__ __align__(16) u16 sP[4][16 * PSP];
    const int tid = threadIdx.x;
    const int bh = blockIdx.x;
    const int b = bh / NH, hh = bh % NH;
    const size_t base = (size_t)bh << 14;
    {
        const us8* vg = (const us8*)(v + base);
        const int t0 = tid >> 3, c8 = tid & 7;
#pragma unroll
        for (int i = 0; i < 8; ++i) {
            int tt = t0 + i * 32;
            us8 vv = vg[tt * 8 + c8];
#pragma unroll
            for (int j = 0; j < 8; ++j)
                sVt[(c8 * 8 + j) * VTP + tt] = vv[j];
        }
    }
    __syncthreads();
    const int w = tid >> 6, lane = tid & 63;
    const int quad = lane >> 4, l16 = lane & 15;
    mfma_in8 aq[4][2];
#pragma unroll
    for (int mt = 0; mt < 4; ++mt) {
        const int t = w + 4 * mt;
        const u16* qp = q + base + (size_t)(16 * t + l16) * NHS + quad * 8;
        aq[mt][0] = *(const mfma_in8*)qp;
        aq[mt][1] = *(const mfma_in8*)(qp + 32);
    }
    f32x4 oa[4][4] = {};
    f32x4 lsum[4] = {};
    const f32x4 zero = {};
    const int jmax = ((w + 12) >> 1) + 1;
    for (int j = 0; j < jmax; ++j) {
        mfma_in8 bv[4];
#pragma unroll
        for (int nt = 0; nt < 4; ++nt)
            bv[nt] = *(const mfma_in8*)&sVt[(nt * 16 + l16) * VTP + j * 32 + quad * 8];
        mfma_in8 bk[2][2];
#pragma unroll
        for (int nt = 0; nt < 2; ++nt) {
            const u16* kp = k + base + (size_t)(j * 32 + nt * 16 + l16) * NHS + quad * 8;
            bk[nt][0] = *(const mfma_in8*)kp;
            bk[nt][1] = *(const mfma_in8*)(kp + 32);
        }
#pragma unroll
        for (int mt = 0; mt < 4; ++mt) {
            const int t = w + 4 * mt;
            const int jm = t >> 1;
            if (j > jm) continue;
            f32x4 s0 = __builtin_amdgcn_mfma_f32_16x16x32_bf16(aq[mt][0], bk[0][0], zero, 0, 0, 0);
            s0 = __builtin_amdgcn_mfma_f32_16x16x32_bf16(aq[mt][1], bk[0][1], s0, 0, 0, 0);
            f32x4 s1 = __builtin_amdgcn_mfma_f32_16x16x32_bf16(aq[mt][0], bk[1][0], zero, 0, 0, 0);
            s1 = __builtin_amdgcn_mfma_f32_16x16x32_bf16(aq[mt][1], bk[1][1], s1, 0, 0, 0);
            float p[2][4];
            const bool boundary = (j == jm);
#pragma unroll
            for (int nt = 0; nt < 2; ++nt)
#pragma unroll
                for (int r = 0; r < 4; ++r) {
                    float sv = (nt ? s1[r] : s0[r]) * SCALE;
                    float e = __expf(sv);
                    if (boundary) {
                        int u = j * 32 + nt * 16 + l16;
                        int R = 16 * t + quad * 4 + r;
                        if (u > R) e = 0.f;
                    }
                    p[nt][r] = e;
                }
            f32x4 rs;
#pragma unroll
            for (int r = 0; r < 4; ++r) rs[r] = p[0][r] + p[1][r];
            rs += shflx4(rs, 1);
            rs += shflx4(rs, 2);
            rs += shflx4(rs, 4);
            rs += shflx4(rs, 8);
            lsum[mt] += rs;
#pragma unroll
            for (int nt = 0; nt < 2; ++nt)
#pragma unroll
                for (int r = 0; r < 4; ++r)
                    sP[w][(quad * 4 + r) * PSP + nt * 16 + l16] = f2bf(p[nt][r]);
            mfma_in8 ap = *(const mfma_in8*)&sP[w][l16 * PSP + quad * 8];
#pragma unroll
            for (int nt = 0; nt < 4; ++nt)
                oa[mt][nt] = __builtin_amdgcn_mfma_f32_16x16x32_bf16(ap, bv[nt], oa[mt][nt], 0, 0, 0);
        }
    }
#pragma unroll
    for (int mt = 0; mt < 4; ++mt) {
        const int t = w + 4 * mt;
        f32x4 inv;
#pragma unroll
        for (int r = 0; r < 4; ++r) inv[r] = 1.f / lsum[mt][r];
#pragma unroll
        for (int nt = 0; nt < 4; ++nt)
#pragma unroll
            for (int r = 0; r < 4; ++r) {
                int row = 16 * t + quad * 4 + r;
                int col = hh * NHS + nt * 16 + l16;
                o[((size_t)(b * NT + row)) * NE + col] = f2bf(oa[mt][nt][r] * inv[r]);
            }
    }
}

// ---------------- loss ------------------------------------------------------------
__global__ __launch_bounds__(256)
void loss_kernel(const float* __restrict__ logits, const int* __restrict__ targets,
                 float* __restrict__ acc) {
    int t = blockIdx.x * 256 + threadIdx.x;
    const float* row = logits + (size_t)t * NV;
    float mx = -1e30f;
    for (int i = 0; i < NV; ++i) mx = fmaxf(mx, row[i]);
    float se = 0.f;
    for (int i = 0; i < NV; ++i) se += __expf(row[i] - mx);
    float li = __logf(se) + mx - row[targets[t]];
#pragma unroll
    for (int off = 32; off >= 1; off >>= 1) li += __shfl_xor(li, off);
    if ((threadIdx.x & 63) == 0) atomicAdd(acc, li);
}
__global__ void loss_final_kernel(const float* __restrict__ acc, float* __restrict__ out) {
    out[0] = acc[0] * (1.f / (float)NM);
}
__global__ void code_kernel(float* __restrict__ out0, float code) {
    if (threadIdx.x == 0 && blockIdx.x == 0) out0[0] = code;
}

// ================================ host ==========================================
extern "C" void kernel_launch(void* const* d_in, const int* in_sizes, int n_in,
                              void* d_out, int out_size, void* d_ws, size_t ws_size,
                              hipStream_t stream) {
    const int*   idx      = (const int*)d_in[0];
    const int*   targets  = (const int*)d_in[1];
    const float* tok_emb  = (const float*)d_in[2];
    const float* pos_emb  = (const float*)d_in[3];
    const float* Wq       = (const float*)d_in[4];
    const float* Wk       = (const float*)d_in[5];
    const float* Wv       = (const float*)d_in[6];
    const float* Wproj    = (const float*)d_in[7];
    const float* bproj    = (const float*)d_in[8];
    const float* ln1_g    = (const float*)d_in[9];
    const float* ln1_b    = (const float*)d_in[10];
    const float* ln2_g    = (const float*)d_in[11];
    const float* ln2_b    = (const float*)d_in[12];
    const float* W1       = (const float*)d_in[13];
    const float* b1       = (const float*)d_in[14];
    const float* W2       = (const float*)d_in[15];
    const float* b2       = (const float*)d_in[16];
    const float* lnf_g    = (const float*)d_in[17];
    const float* lnf_b    = (const float*)d_in[18];
    const float* Wlm      = (const float*)d_in[19];
    const float* blm      = (const float*)d_in[20];
    float* out = (float*)d_out;

    static const int expect[21] = {
        16384, 16384, 24960, 98304, 884736, 884736, 884736, 884736, 2304,
        2304, 2304, 2304, 2304, 3538944, 9216, 3538944, 2304, 384, 384,
        24960, 65};
    if (n_in < 21) { code_kernel<<<1, 1, 0, stream>>>(out, 990.f); return; }
    for (int i = 0; i < 21; ++i)
        if (in_sizes[i] != expect[i]) {
            code_kernel<<<1, 1, 0, stream>>>(out, 1000.f + 10.f * i);
            return;
        }

    // ---- workspace layout (~97 MB) ----
    char* ws = (char*)d_ws;
    size_t off = 0;
    auto alloc = [&](size_t bytes) -> void* {
        void* p = ws + off;
        off += (bytes + 255) & ~(size_t)255;
        return p;
    };
    const size_t S = (size_t)NM * NE * 2;          // 12.58 MB
    float* lossacc = (float*)alloc(256);
    u16*   x       = (u16*)alloc(S);               // bf16 residual master
    u16*   h       = (u16*)alloc(S);
    u16*   region  = (u16*)alloc(4 * S);           // q|k|v|o, overlaid by ub
    u16*   qb = region;
    u16*   kb = region + NM * NE;
    u16*   vb = region + 2 * (size_t)NM * NE;
    u16*   ob = region + 3 * (size_t)NM * NE;
    u16*   ub = region;
    u16* WqkvT  = (u16*)alloc((size_t)NL * 3 * NE * NE * 2);
    u16* WprojT = (u16*)alloc((size_t)NL * NE * NE * 2);
    u16* W1T    = (u16*)alloc((size_t)NL * NE * 4 * NE * 2);
    u16* W2T    = (u16*)alloc((size_t)NL * NE * 4 * NE * 2);
    u16* WlmT   = (u16*)alloc((size_t)80 * NE * 2);

    if (ws_size < off) { code_kernel<<<1, 1, 0, stream>>>(out, 999.f); return; }

    hipMemsetAsync(lossacc, 0, 4, stream);
    embed_kernel<<<(NM * NE) / 256, 256, 0, stream>>>(idx, tok_emb, pos_emb, x);

    convQKV_kernel<<<(NL * 3 * NH * NE * NHS) / 256, 256, 0, stream>>>(Wq, Wk, Wv, WqkvT);
    convT_kernel<<<dim3((NE * NE + 255) / 256, NL), 256, 0, stream>>>(Wproj, WprojT, NE, NE);
    convT_kernel<<<dim3((NE * 4 * NE + 255) / 256, NL), 256, 0, stream>>>(W1, W1T, NE, 4 * NE);
    convT_kernel<<<dim3((NE * 4 * NE + 255) / 256, NL), 256, 0, stream>>>(W2, W2T, 4 * NE, NE);
    convLM_kernel<<<(80 * NE + 255) / 256, 256, 0, stream>>>(Wlm, WlmT);

    const int gLN = NM / 16;
    const int nbm = NM / 128;
    for (int l = 0; l < NL; ++l) {
        ln_kernel<<<gLN, 256, 0, stream>>>(x, ln1_g + l * NE, ln1_b + l * NE, h);
        gemm_qkv_f<<<nbm * (3 * NE / 128), 256, 0, stream>>>(
            h, WqkvT + (size_t)l * 3 * NE * NE, qb, kb, vb);
        attn_kernel<<<NB * NH, 256, 0, stream>>>(qb, kb, vb, ob);
        gemm_resid_f<<<nbm * (NE / 64), 256, 0, stream>>>(
            ob, WprojT + (size_t)l * NE * NE, NE, NE, bproj + l * NE, x);
        ln_kernel<<<gLN, 256, 0, stream>>>(x, ln2_g + l * NE, ln2_b + l * NE, h);
        gemm_relu_f<<<nbm * (4 * NE / 128), 256, 0, stream>>>(
            h, W1T + (size_t)l * NE * 4 * NE, 4 * NE, NE, b1 + l * 4 * NE, ub);
        gemm_resid_f<<<nbm * (NE / 64), 256, 0, stream>>>(
            ub, W2T + (size_t)l * NE * 4 * NE, NE, 4 * NE, b2 + l * NE, x);
    }

    ln_kernel<<<gLN, 256, 0, stream>>>(x, lnf_g, lnf_b, h);
    lmhead_f<<<NM / 64, 256, 0, stream>>>(h, WlmT, blm, out);
    loss_kernel<<<NM / 256, 256, 0, stream>>>(out, targets, lossacc);
    if (out_size > NM * NV)
        loss_final_kernel<<<1, 1, 0, stream>>>(lossacc, out + (size_t)NM * NV);
}

// Round 13
// 1103.598 us; speedup vs baseline: 11.1307x; 1.0436x over previous
//
#include <hip/hip_runtime.h>
#include <hip/hip_bf16.h>

typedef unsigned short u16;
typedef __attribute__((ext_vector_type(8))) unsigned short us8;
typedef __attribute__((ext_vector_type(8))) short mfma_in8;   // 8 bf16 in 4 VGPRs
typedef __attribute__((ext_vector_type(4))) float f32x4;

#define NL 6
#define NH 6
#define NE 384
#define NHS 64
#define NT 256
#define NB 64
#define NV 65
#define NM (NB * NT)          // 16384 tokens
#define SCALE 0.051031036307982884f   // 384^-0.5
#define VTP 264               // V^T LDS row stride (u16)
#define PSP 44                // P-tile LDS row stride (u16)

static __device__ __forceinline__ float bf2f(u16 u) {
    return __uint_as_float(((unsigned int)u) << 16);
}
static __device__ __forceinline__ u16 f2bf(float f) {
    unsigned int x = __float_as_uint(f);
    unsigned int r = x + 0x7fffu + ((x >> 16) & 1u);   // RNE
    return (u16)(r >> 16);
}
static __device__ __forceinline__ void llds16(const u16* g, u16* l) {
    __builtin_amdgcn_global_load_lds(
        (const __attribute__((address_space(1))) void*)g,
        (__attribute__((address_space(3))) void*)l, 16, 0, 0);
}

// ---------------- embedding: x(bf16) = tok_emb[idx] + pos_emb --------------------
__global__ __launch_bounds__(256)
void embed_kernel(const int* __restrict__ idx, const float* __restrict__ tok,
                  const float* __restrict__ pos, u16* __restrict__ x) {
    int gid = blockIdx.x * 256 + threadIdx.x;          // over NM*NE
    int bt = gid / NE, e = gid % NE;
    int t = bt & (NT - 1);
    x[gid] = f2bf(tok[idx[bt] * NE + e] + pos[t * NE + e]);
}

// ---------------- LayerNorm (plain): bf16 x -> bf16 h ----------------------------
__global__ __launch_bounds__(256)
void ln_kernel(const u16* __restrict__ x, const float* __restrict__ g,
               const float* __restrict__ b, u16* __restrict__ out) {
    const int sub = threadIdx.x & 15;
    const int token = blockIdx.x * 16 + (threadIdx.x >> 4);
    const u16* row = x + (size_t)token * NE + sub * 24;
    us8 v0 = *(const us8*)row;
    us8 v1 = *(const us8*)(row + 8);
    us8 v2 = *(const us8*)(row + 16);
    float vals[24];
#pragma unroll
    for (int j = 0; j < 8; ++j) {
        vals[j] = bf2f(v0[j]); vals[8 + j] = bf2f(v1[j]); vals[16 + j] = bf2f(v2[j]);
    }
    float s = 0.f;
#pragma unroll
    for (int j = 0; j < 24; ++j) s += vals[j];
#pragma unroll
    for (int off = 8; off >= 1; off >>= 1) s += __shfl_xor(s, off);
    float mean = s * (1.f / NE);
    float s2 = 0.f;
#pragma unroll
    for (int j = 0; j < 24; ++j) { float d = vals[j] - mean; s2 += d * d; }
#pragma unroll
    for (int off = 8; off >= 1; off >>= 1) s2 += __shfl_xor(s2, off);
    float inv = rsqrtf(s2 * (1.f / NE) + 1e-5f);
    const float* gp = g + sub * 24;
    const float* bp = b + sub * 24;
    us8 o0, o1, o2;
#pragma unroll
    for (int j = 0; j < 8; ++j) {
        o0[j] = f2bf((vals[j] - mean) * inv * gp[j] + bp[j]);
        o1[j] = f2bf((vals[8 + j] - mean) * inv * gp[8 + j] + bp[8 + j]);
        o2[j] = f2bf((vals[16 + j] - mean) * inv * gp[16 + j] + bp[16 + j]);
    }
    u16* orow = out + (size_t)token * NE + sub * 24;
    *(us8*)orow = o0;
    *(us8*)(orow + 8) = o1;
    *(us8*)(orow + 16) = o2;
}

// ---------------- fused residual-add + LayerNorm ---------------------------------
// x += c (bf16 writeback); h = LN(x_f32) — one pass over both tensors.
__global__ __launch_bounds__(256)
void ln_add_kernel(u16* __restrict__ x, const u16* __restrict__ c,
                   const float* __restrict__ g, const float* __restrict__ b,
                   u16* __restrict__ out) {
    const int sub = threadIdx.x & 15;
    const int token = blockIdx.x * 16 + (threadIdx.x >> 4);
    const size_t base = (size_t)token * NE + sub * 24;
    u16* xrow = x + base;
    const u16* crow = c + base;
    us8 xv0 = *(const us8*)xrow;
    us8 xv1 = *(const us8*)(xrow + 8);
    us8 xv2 = *(const us8*)(xrow + 16);
    us8 cv0 = *(const us8*)crow;
    us8 cv1 = *(const us8*)(crow + 8);
    us8 cv2 = *(const us8*)(crow + 16);
    float vals[24];
#pragma unroll
    for (int j = 0; j < 8; ++j) {
        vals[j]      = bf2f(xv0[j]) + bf2f(cv0[j]);
        vals[8 + j]  = bf2f(xv1[j]) + bf2f(cv1[j]);
        vals[16 + j] = bf2f(xv2[j]) + bf2f(cv2[j]);
    }
    us8 nx0, nx1, nx2;
#pragma unroll
    for (int j = 0; j < 8; ++j) {
        nx0[j] = f2bf(vals[j]); nx1[j] = f2bf(vals[8 + j]); nx2[j] = f2bf(vals[16 + j]);
    }
    *(us8*)xrow = nx0;
    *(us8*)(xrow + 8) = nx1;
    *(us8*)(xrow + 16) = nx2;
    float s = 0.f;
#pragma unroll
    for (int j = 0; j < 24; ++j) s += vals[j];
#pragma unroll
    for (int off = 8; off >= 1; off >>= 1) s += __shfl_xor(s, off);
    float mean = s * (1.f / NE);
    float s2 = 0.f;
#pragma unroll
    for (int j = 0; j < 24; ++j) { float d = vals[j] - mean; s2 += d * d; }
#pragma unroll
    for (int off = 8; off >= 1; off >>= 1) s2 += __shfl_xor(s2, off);
    float inv = rsqrtf(s2 * (1.f / NE) + 1e-5f);
    const float* gp = g + sub * 24;
    const float* bp = b + sub * 24;
    us8 o0, o1, o2;
#pragma unroll
    for (int j = 0; j < 8; ++j) {
        o0[j] = f2bf((vals[j] - mean) * inv * gp[j] + bp[j]);
        o1[j] = f2bf((vals[8 + j] - mean) * inv * gp[8 + j] + bp[8 + j]);
        o2[j] = f2bf((vals[16 + j] - mean) * inv * gp[16 + j] + bp[16 + j]);
    }
    u16* orow = out + base;
    *(us8*)orow = o0;
    *(us8*)(orow + 8) = o1;
    *(us8*)(orow + 16) = o2;
}

// ---------------- weight conversion -----------------------------------------------
__global__ __launch_bounds__(256)
void convQKV_kernel(const float* __restrict__ Wq, const float* __restrict__ Wk,
                    const float* __restrict__ Wv, u16* __restrict__ dst) {
    int i = blockIdx.x * 256 + threadIdx.x;            // over NL*3*NH*NE*NHS
    int s = i & 63; int rest = i >> 6;
    int e = rest % NE; rest /= NE;
    int hh = rest % NH; rest /= NH;
    int which = rest % 3; int l = rest / 3;
    const float* W = which == 0 ? Wq : which == 1 ? Wk : Wv;
    float v = W[((size_t)(l * NH + hh) * NE + e) * NHS + s];
    dst[((size_t)l * 3 * NE + which * NE + hh * NHS + s) * NE + e] = f2bf(v);
}
__global__ __launch_bounds__(256)
void convT_kernel(const float* __restrict__ src, u16* __restrict__ dst,
                  int K, int N) {
    const float* s = src + (size_t)blockIdx.y * K * N;
    u16* d = dst + (size_t)blockIdx.y * K * N;
    int i = blockIdx.x * 256 + threadIdx.x;
    if (i >= K * N) return;
    int k = i / N, n = i % N;
    d[(size_t)n * K + k] = f2bf(s[i]);
}
__global__ __launch_bounds__(256)
void convLM_kernel(const float* __restrict__ Wlm, u16* __restrict__ dst) {
    int i = blockIdx.x * 256 + threadIdx.x;            // over 80*NE
    if (i >= 80 * NE) return;
    int n = i / NE, k = i % NE;
    dst[i] = f2bf(n < NV ? Wlm[(size_t)k * NV + n] : 0.f);
}

// ---------------- 128x128 MFMA core, double-buffered LDS pipeline ----------------
static __device__ __forceinline__ void gemm128_core(
        const u16* __restrict__ A, const u16* __restrict__ BT,
        int m0, int n0, int K, f32x4 acc[4][4]) {
    __shared__ __align__(16) u16 smA[2][128 * 32];
    __shared__ __align__(16) u16 smB[2][128 * 32];
    const int tid = threadIdx.x;
    const int wv = tid >> 6, lane = tid & 63;
    const int wm = wv & 1, wn = wv >> 1;
    const int quad = lane >> 4, l16 = lane & 15;
    const int c0 = tid, c1 = tid + 256;
    const size_t aoff0 = (size_t)(m0 + (c0 >> 2)) * K + ((c0 & 3) << 3);
    const size_t aoff1 = (size_t)(m0 + (c1 >> 2)) * K + ((c1 & 3) << 3);
    const size_t boff0 = (size_t)(n0 + (c0 >> 2)) * K + ((c0 & 3) << 3);
    const size_t boff1 = (size_t)(n0 + (c1 >> 2)) * K + ((c1 & 3) << 3);
    llds16(A + aoff0, smA[0] + c0 * 8);
    llds16(A + aoff1, smA[0] + c1 * 8);
    llds16(BT + boff0, smB[0] + c0 * 8);
    llds16(BT + boff1, smB[0] + c1 * 8);
    __syncthreads();
    const int nk = K >> 5;
    for (int ki = 0; ki < nk; ++ki) {
        const int cur = ki & 1, nxt = cur ^ 1;
        if (ki + 1 < nk) {
            const int k0 = (ki + 1) << 5;
            llds16(A + aoff0 + k0, smA[nxt] + c0 * 8);
            llds16(A + aoff1 + k0, smA[nxt] + c1 * 8);
            llds16(BT + boff0 + k0, smB[nxt] + c0 * 8);
            llds16(BT + boff1 + k0, smB[nxt] + c1 * 8);
        }
        mfma_in8 af[4], bf[4];
#pragma unroll
        for (int im = 0; im < 4; ++im)
            af[im] = *(const mfma_in8*)&smA[cur][(wm * 64 + im * 16 + l16) * 32 + quad * 8];
#pragma unroll
        for (int in = 0; in < 4; ++in)
            bf[in] = *(const mfma_in8*)&smB[cur][(wn * 64 + in * 16 + l16) * 32 + quad * 8];
#pragma unroll
        for (int im = 0; im < 4; ++im)
#pragma unroll
            for (int in = 0; in < 4; ++in)
                acc[im][in] = __builtin_amdgcn_mfma_f32_16x16x32_bf16(
                    af[im], bf[in], acc[im][in], 0, 0, 0);
        __syncthreads();
    }
}

__global__ __launch_bounds__(256)
void gemm_qkv_f(const u16* __restrict__ A, const u16* __restrict__ BT,
                u16* __restrict__ qout, u16* __restrict__ kout,
                u16* __restrict__ vout) {
    const int nbm = NM >> 7;
    const int bm = blockIdx.x % nbm, bn = blockIdx.x / nbm;
    const int m0 = bm << 7, n0 = bn << 7;              // N=1152
    f32x4 acc[4][4] = {};
    gemm128_core(A, BT, m0, n0, NE, acc);
    const int lane = threadIdx.x & 63, wv = threadIdx.x >> 6;
    const int wm = wv & 1, wn = wv >> 1;
    const int quad = lane >> 4, l16 = lane & 15;
#pragma unroll
    for (int im = 0; im < 4; ++im)
#pragma unroll
        for (int in = 0; in < 4; ++in)
#pragma unroll
            for (int r = 0; r < 4; ++r) {
                int row = m0 + wm * 64 + im * 16 + quad * 4 + r;
                int col = n0 + wn * 64 + in * 16 + l16;
                int which = col / NE, j = col % NE;
                int hh = j >> 6, s = j & 63;
                int bb = row >> 8, tt = row & 255;
                u16* dst = (which == 0) ? qout : (which == 1) ? kout : vout;
                dst[((((size_t)bb * NH + hh) << 8) + tt) * NHS + s] =
                    f2bf(acc[im][in][r]);
            }
}

__global__ __launch_bounds__(256)
void gemm_relu_f(const u16* __restrict__ A, const u16* __restrict__ BT,
                 const int N, const int K,
                 const float* __restrict__ bias, u16* __restrict__ outb) {
    const int nbm = NM >> 7;
    const int bm = blockIdx.x % nbm, bn = blockIdx.x / nbm;
    const int m0 = bm << 7, n0 = bn << 7;
    f32x4 acc[4][4] = {};
    gemm128_core(A, BT, m0, n0, K, acc);
    const int lane = threadIdx.x & 63, wv = threadIdx.x >> 6;
    const int wm = wv & 1, wn = wv >> 1;
    const int quad = lane >> 4, l16 = lane & 15;
#pragma unroll
    for (int im = 0; im < 4; ++im)
#pragma unroll
        for (int in = 0; in < 4; ++in)
#pragma unroll
            for (int r = 0; r < 4; ++r) {
                int row = m0 + wm * 64 + im * 16 + quad * 4 + r;
                int col = n0 + wn * 64 + in * 16 + l16;
                outb[(size_t)row * N + col] =
                    f2bf(fmaxf(acc[im][in][r] + bias[col], 0.f));
            }
}

// ---------------- 128x64 MFMA core, double-buffered -------------------------------
static __device__ __forceinline__ void gemm64_core(
        const u16* __restrict__ A, const u16* __restrict__ BT,
        int m0, int n0, int K, f32x4 acc[4][2]) {
    __shared__ __align__(16) u16 smA[2][128 * 32];
    __shared__ __align__(16) u16 smB[2][64 * 32];
    const int tid = threadIdx.x;
    const int wv = tid >> 6, lane = tid & 63;
    const int wm = wv & 1, wn = wv >> 1;
    const int quad = lane >> 4, l16 = lane & 15;
    const int c0 = tid, c1 = tid + 256;
    const size_t aoff0 = (size_t)(m0 + (c0 >> 2)) * K + ((c0 & 3) << 3);
    const size_t aoff1 = (size_t)(m0 + (c1 >> 2)) * K + ((c1 & 3) << 3);
    const size_t boff0 = (size_t)(n0 + (c0 >> 2)) * K + ((c0 & 3) << 3);
    llds16(A + aoff0, smA[0] + c0 * 8);
    llds16(A + aoff1, smA[0] + c1 * 8);
    llds16(BT + boff0, smB[0] + c0 * 8);
    __syncthreads();
    const int nk = K >> 5;
    for (int ki = 0; ki < nk; ++ki) {
        const int cur = ki & 1, nxt = cur ^ 1;
        if (ki + 1 < nk) {
            const int k0 = (ki + 1) << 5;
            llds16(A + aoff0 + k0, smA[nxt] + c0 * 8);
            llds16(A + aoff1 + k0, smA[nxt] + c1 * 8);
            llds16(BT + boff0 + k0, smB[nxt] + c0 * 8);
        }
        mfma_in8 af[4], bf[2];
#pragma unroll
        for (int im = 0; im < 4; ++im)
            af[im] = *(const mfma_in8*)&smA[cur][(wm * 64 + im * 16 + l16) * 32 + quad * 8];
#pragma unroll
        for (int in = 0; in < 2; ++in)
            bf[in] = *(const mfma_in8*)&smB[cur][(wn * 32 + in * 16 + l16) * 32 + quad * 8];
#pragma unroll
        for (int im = 0; im < 4; ++im)
#pragma unroll
            for (int in = 0; in < 2; ++in)
                acc[im][in] = __builtin_amdgcn_mfma_f32_16x16x32_bf16(
                    af[im], bf[in], acc[im][in], 0, 0, 0);
        __syncthreads();
    }
}

// write-only C epilogue: cb = C + bias (residual add deferred to ln_add)
__global__ __launch_bounds__(256)
void gemm_c_f(const u16* __restrict__ A, const u16* __restrict__ BT,
              const int N, const int K,
              const float* __restrict__ bias, u16* __restrict__ cb) {
    const int nbm = NM >> 7;
    const int bm = blockIdx.x % nbm, bn = blockIdx.x / nbm;
    const int m0 = bm << 7, n0 = bn << 6;
    f32x4 acc[4][2] = {};
    gemm64_core(A, BT, m0, n0, K, acc);
    const int lane = threadIdx.x & 63, wv = threadIdx.x >> 6;
    const int wm = wv & 1, wn = wv >> 1;
    const int quad = lane >> 4, l16 = lane & 15;
#pragma unroll
    for (int im = 0; im < 4; ++im)
#pragma unroll
        for (int in = 0; in < 2; ++in)
#pragma unroll
            for (int r = 0; r < 4; ++r) {
                int row = m0 + wm * 64 + im * 16 + quad * 4 + r;
                int col = n0 + wn * 32 + in * 16 + l16;
                cb[(size_t)row * N + col] = f2bf(acc[im][in][r] + bias[col]);
            }
}

// ---------------- fast lmhead ----------------------------------------------------
__global__ __launch_bounds__(256)
void lmhead_f(const u16* __restrict__ xf, const u16* __restrict__ WlmT,
              const float* __restrict__ blm, float* __restrict__ out) {
    const int w = threadIdx.x >> 6, lane = threadIdx.x & 63;
    const int quad = lane >> 4, l16 = lane & 15;
    const int m0 = (blockIdx.x * 4 + w) * 16;
    f32x4 acc[5] = {};
#pragma unroll 2
    for (int k0 = 0; k0 < NE; k0 += 32) {
        mfma_in8 a = *(const mfma_in8*)(xf + (size_t)(m0 + l16) * NE + k0 + quad * 8);
#pragma unroll
        for (int nt = 0; nt < 5; ++nt) {
            mfma_in8 b = *(const mfma_in8*)(WlmT + (size_t)(nt * 16 + l16) * NE + k0 + quad * 8);
            acc[nt] = __builtin_amdgcn_mfma_f32_16x16x32_bf16(a, b, acc[nt], 0, 0, 0);
        }
    }
#pragma unroll
    for (int nt = 0; nt < 5; ++nt) {
        int col = nt * 16 + l16;
        if (col < NV) {
            float bb = blm[col];
#pragma unroll
            for (int r = 0; r < 4; ++r)
                out[(size_t)(m0 + quad * 4 + r) * NV + col] = acc[nt][r] + bb;
        }
    }
}

// ---------------- MFMA flash attention (unchanged) --------------------------------
static __device__ __forceinline__ f32x4 shflx4(f32x4 v, int off) {
    f32x4 r;
#pragma unroll
    for (int i = 0; i < 4; ++i) r[i] = __shfl_xor(v[i], off);
    return r;
}
__global__ __launch_bounds__(256)
void attn_kernel(const u16* __restrict__ q, const u16* __restrict__ k,
                 const u16* __restrict__ v, u16* __restrict__ o) {
    __shared__ __align__(16) u16 sVt[64 * VTP];
    __shared__ __align__(16) u16 sP[4][16 * PSP];
    const int tid = threadIdx.x;
    const int bh = blockIdx.x;
    const int b = bh / NH, hh = bh % NH;
    const size_t base = (size_t)bh << 14;
    {
        const us8* vg = (const us8*)(v + base);
        const int t0 = tid >> 3, c8 = tid & 7;
#pragma unroll
        for (int i = 0; i < 8; ++i) {
            int tt = t0 + i * 32;
            us8 vv = vg[tt * 8 + c8];
#pragma unroll
            for (int j = 0; j < 8; ++j)
                sVt[(c8 * 8 + j) * VTP + tt] = vv[j];
        }
    }
    __syncthreads();
    const int w = tid >> 6, lane = tid & 63;
    const int quad = lane >> 4, l16 = lane & 15;
    mfma_in8 aq[4][2];
#pragma unroll
    for (int mt = 0; mt < 4; ++mt) {
        const int t = w + 4 * mt;
        const u16* qp = q + base + (size_t)(16 * t + l16) * NHS + quad * 8;
        aq[mt][0] = *(const mfma_in8*)qp;
        aq[mt][1] = *(const mfma_in8*)(qp + 32);
    }
    f32x4 oa[4][4] = {};
    f32x4 lsum[4] = {};
    const f32x4 zero = {};
    const int jmax = ((w + 12) >> 1) + 1;
    for (int j = 0; j < jmax; ++j) {
        mfma_in8 bv[4];
#pragma unroll
        for (int nt = 0; nt < 4; ++nt)
            bv[nt] = *(const mfma_in8*)&sVt[(nt * 16 + l16) * VTP + j * 32 + quad * 8];
        mfma_in8 bk[2][2];
#pragma unroll
        for (int nt = 0; nt < 2; ++nt) {
            const u16* kp = k + base + (size_t)(j * 32 + nt * 16 + l16) * NHS + quad * 8;
            bk[nt][0] = *(const mfma_in8*)kp;
            bk[nt][1] = *(const mfma_in8*)(kp + 32);
        }
#pragma unroll
        for (int mt = 0; mt < 4; ++mt) {
            const int t = w + 4 * mt;
            const int jm = t >> 1;
            if (j > jm) continue;
            f32x4 s0 = __builtin_amdgcn_mfma_f32_16x16x32_bf16(aq[mt][0], bk[0][0], zero, 0, 0, 0);
            s0 = __builtin_amdgcn_mfma_f32_16x16x32_bf16(aq[mt][1], bk[0][1], s0, 0, 0, 0);
            f32x4 s1 = __builtin_amdgcn_mfma_f32_16x16x32_bf16(aq[mt][0], bk[1][0], zero, 0, 0, 0);
            s1 = __builtin_amdgcn_mfma_f32_16x16x32_bf16(aq[mt][1], bk[1][1], s1, 0, 0, 0);
            float p[2][4];
            const bool boundary = (j == jm);
#pragma unroll
            for (int nt = 0; nt < 2; ++nt)
#pragma unroll
                for (int r = 0; r < 4; ++r) {
                    float sv = (nt ? s1[r] : s0[r]) * SCALE;
                    float e = __expf(sv);
                    if (boundary) {
                        int u = j * 32 + nt * 16 + l16;
                        int R = 16 * t + quad * 4 + r;
                        if (u > R) e = 0.f;
                    }
                    p[nt][r] = e;
                }
            f32x4 rs;
#pragma unroll
            for (int r = 0; r < 4; ++r) rs[r] = p[0][r] + p[1][r];
            rs += shflx4(rs, 1);
            rs += shflx4(rs, 2);
            rs += shflx4(rs, 4);
            rs += shflx4(rs, 8);
            lsum[mt] += rs;
#pragma unroll
            for (int nt = 0; nt < 2; ++nt)
#pragma unroll
                for (int r = 0; r < 4; ++r)
                    sP[w][(quad * 4 + r) * PSP + nt * 16 + l16] = f2bf(p[nt][r]);
            mfma_in8 ap = *(const mfma_in8*)&sP[w][l16 * PSP + quad * 8];
#pragma unroll
            for (int nt = 0; nt < 4; ++nt)
                oa[mt][nt] = __builtin_amdgcn_mfma_f32_16x16x32_bf16(ap, bv[nt], oa[mt][nt], 0, 0, 0);
        }
    }
#pragma unroll
    for (int mt = 0; mt < 4; ++mt) {
        const int t = w + 4 * mt;
        f32x4 inv;
#pragma unroll
        for (int r = 0; r < 4; ++r) inv[r] = 1.f / lsum[mt][r];
#pragma unroll
        for (int nt = 0; nt < 4; ++nt)
#pragma unroll
            for (int r = 0; r < 4; ++r) {
                int row = 16 * t + quad * 4 + r;
                int col = hh * NHS + nt * 16 + l16;
                o[((size_t)(b * NT + row)) * NE + col] = f2bf(oa[mt][nt][r] * inv[r]);
            }
    }
}

// ---------------- loss ------------------------------------------------------------
__global__ __launch_bounds__(256)
void loss_kernel(const float* __restrict__ logits, const int* __restrict__ targets,
                 float* __restrict__ acc) {
    int t = blockIdx.x * 256 + threadIdx.x;
    const float* row = logits + (size_t)t * NV;
    float mx = -1e30f;
    for (int i = 0; i < NV; ++i) mx = fmaxf(mx, row[i]);
    float se = 0.f;
    for (int i = 0; i < NV; ++i) se += __expf(row[i] - mx);
    float li = __logf(se) + mx - row[targets[t]];
#pragma unroll
    for (int off = 32; off >= 1; off >>= 1) li += __shfl_xor(li, off);
    if ((threadIdx.x & 63) == 0) atomicAdd(acc, li);
}
__global__ void loss_final_kernel(const float* __restrict__ acc, float* __restrict__ out) {
    out[0] = acc[0] * (1.f / (float)NM);
}
__global__ void code_kernel(float* __restrict__ out0, float code) {
    if (threadIdx.x == 0 && blockIdx.x == 0) out0[0] = code;
}

// ================================ host ==========================================
extern "C" void kernel_launch(void* const* d_in, const int* in_sizes, int n_in,
                              void* d_out, int out_size, void* d_ws, size_t ws_size,
                              hipStream_t stream) {
    const int*   idx      = (const int*)d_in[0];
    const int*   targets  = (const int*)d_in[1];
    const float* tok_emb  = (const float*)d_in[2];
    const float* pos_emb  = (const float*)d_in[3];
    const float* Wq       = (const float*)d_in[4];
    const float* Wk       = (const float*)d_in[5];
    const float* Wv       = (const float*)d_in[6];
    const float* Wproj    = (const float*)d_in[7];
    const float* bproj    = (const float*)d_in[8];
    const float* ln1_g    = (const float*)d_in[9];
    const float* ln1_b    = (const float*)d_in[10];
    const float* ln2_g    = (const float*)d_in[11];
    const float* ln2_b    = (const float*)d_in[12];
    const float* W1       = (const float*)d_in[13];
    const float* b1       = (const float*)d_in[14];
    const float* W2       = (const float*)d_in[15];
    const float* b2       = (const float*)d_in[16];
    const float* lnf_g    = (const float*)d_in[17];
    const float* lnf_b    = (const float*)d_in[18];
    const float* Wlm      = (const float*)d_in[19];
    const float* blm      = (const float*)d_in[20];
    float* out = (float*)d_out;

    static const int expect[21] = {
        16384, 16384, 24960, 98304, 884736, 884736, 884736, 884736, 2304,
        2304, 2304, 2304, 2304, 3538944, 9216, 3538944, 2304, 384, 384,
        24960, 65};
    if (n_in < 21) { code_kernel<<<1, 1, 0, stream>>>(out, 990.f); return; }
    for (int i = 0; i < 21; ++i)
        if (in_sizes[i] != expect[i]) {
            code_kernel<<<1, 1, 0, stream>>>(out, 1000.f + 10.f * i);
            return;
        }

    // ---- workspace layout (~117 MB) ----
    char* ws = (char*)d_ws;
    size_t off = 0;
    auto alloc = [&](size_t bytes) -> void* {
        void* p = ws + off;
        off += (bytes + 255) & ~(size_t)255;
        return p;
    };
    const size_t S = (size_t)NM * NE * 2;          // 12.58 MB
    float* lossacc = (float*)alloc(256);
    u16*   x       = (u16*)alloc(S);               // bf16 residual master
    u16*   h       = (u16*)alloc(S);
    u16*   cb      = (u16*)alloc(S);               // GEMM C output (pre-residual)
    u16*   region  = (u16*)alloc(4 * S);           // q|k|v|o, overlaid by ub
    u16*   qb = region;
    u16*   kb = region + NM * NE;
    u16*   vb = region + 2 * (size_t)NM * NE;
    u16*   ob = region + 3 * (size_t)NM * NE;
    u16*   ub = region;
    u16* WqkvT  = (u16*)alloc((size_t)NL * 3 * NE * NE * 2);
    u16* WprojT = (u16*)alloc((size_t)NL * NE * NE * 2);
    u16* W1T    = (u16*)alloc((size_t)NL * NE * 4 * NE * 2);
    u16* W2T    = (u16*)alloc((size_t)NL * NE * 4 * NE * 2);
    u16* WlmT   = (u16*)alloc((size_t)80 * NE * 2);

    if (ws_size < off) { code_kernel<<<1, 1, 0, stream>>>(out, 999.f); return; }

    hipMemsetAsync(lossacc, 0, 4, stream);
    embed_kernel<<<(NM * NE) / 256, 256, 0, stream>>>(idx, tok_emb, pos_emb, x);

    convQKV_kernel<<<(NL * 3 * NH * NE * NHS) / 256, 256, 0, stream>>>(Wq, Wk, Wv, WqkvT);
    convT_kernel<<<dim3((NE * NE + 255) / 256, NL), 256, 0, stream>>>(Wproj, WprojT, NE, NE);
    convT_kernel<<<dim3((NE * 4 * NE + 255) / 256, NL), 256, 0, stream>>>(W1, W1T, NE, 4 * NE);
    convT_kernel<<<dim3((NE * 4 * NE + 255) / 256, NL), 256, 0, stream>>>(W2, W2T, 4 * NE, NE);
    convLM_kernel<<<(80 * NE + 255) / 256, 256, 0, stream>>>(Wlm, WlmT);

    const int gLN = NM / 16;
    const int nbm = NM / 128;
    for (int l = 0; l < NL; ++l) {
        if (l == 0)
            ln_kernel<<<gLN, 256, 0, stream>>>(x, ln1_g, ln1_b, h);
        else
            ln_add_kernel<<<gLN, 256, 0, stream>>>(x, cb, ln1_g + l * NE,
                                                   ln1_b + l * NE, h);
        gemm_qkv_f<<<nbm * (3 * NE / 128), 256, 0, stream>>>(
            h, WqkvT + (size_t)l * 3 * NE * NE, qb, kb, vb);
        attn_kernel<<<NB * NH, 256, 0, stream>>>(qb, kb, vb, ob);
        gemm_c_f<<<nbm * (NE / 64), 256, 0, stream>>>(
            ob, WprojT + (size_t)l * NE * NE, NE, NE, bproj + l * NE, cb);
        ln_add_kernel<<<gLN, 256, 0, stream>>>(x, cb, ln2_g + l * NE,
                                               ln2_b + l * NE, h);
        gemm_relu_f<<<nbm * (4 * NE / 128), 256, 0, stream>>>(
            h, W1T + (size_t)l * NE * 4 * NE, 4 * NE, NE, b1 + l * 4 * NE, ub);
        gemm_c_f<<<nbm * (NE / 64), 256, 0, stream>>>(
            ub, W2T + (size_t)l * NE * 4 * NE, NE, 4 * NE, b2 + l * NE, cb);
    }

    ln_add_kernel<<<gLN, 256, 0, stream>>>(x, cb, lnf_g, lnf_b, h);
    lmhead_f<<<NM / 64, 256, 0, stream>>>(h, WlmT, blm, out);
    loss_kernel<<<NM / 256, 256, 0, stream>>>(out, targets, lossacc);
    if (out_size > NM * NV)
        loss_final_kernel<<<1, 1, 0, stream>>>(lossacc, out + (size_t)NM * NV);
}